// Round 1
// baseline (11072.578 us; speedup 1.0000x reference)
//
#include <hip/hip_runtime.h>

#define NN 50000
#define NE 400000
#define BB 2
#define ROWS (NN * BB)   // 100000 feature rows, row r = node*2 + batch

// ---------------- kernels ----------------

__global__ void k_deg(const int* __restrict__ dst, float* __restrict__ deg) {
    int e = blockIdx.x * 256 + threadIdx.x;
    if (e < NE) atomicAdd(&deg[dst[e]], 1.0f);
}

__global__ void k_rdeg(float* __restrict__ deg) {
    int n = blockIdx.x * 256 + threadIdx.x;
    if (n < NN) deg[n] = 1.0f / fmaxf(deg[n], 1.0f);
}

// in_feat [B,N,64] -> h [N*B, 64]
__global__ void k_tin(const float4* __restrict__ in, float4* __restrict__ out) {
    int t = blockIdx.x * 256 + threadIdx.x;
    if (t >= ROWS * 16) return;
    int r = t >> 4, c = t & 15;
    int n = r >> 1, b = r & 1;
    out[t] = in[(b * NN + n) * 16 + c];
}

// scatter-add x[src] into agg[dst]; per-node payload = (1<<cshift) float4s
__global__ void k_agg(const float4* __restrict__ x, const int* __restrict__ src,
                      const int* __restrict__ dst, float* __restrict__ agg, int cshift) {
    int t = blockIdx.x * 256 + threadIdx.x;
    int total = NE << cshift;
    if (t >= total) return;
    int e = t >> cshift, c = t & ((1 << cshift) - 1);
    float4 v = x[(src[e] << cshift) + c];
    float* a = agg + (((dst[e] << cshift) + c) << 2);
    atomicAdd(a + 0, v.x);
    atomicAdd(a + 1, v.y);
    atomicAdd(a + 2, v.z);
    atomicAdd(a + 3, v.w);
}

// plain z = x @ w   (x: [ROWS, fin], w: [fin, fout] row-major)
__global__ void k_mm(const float* __restrict__ x, const float* __restrict__ w,
                     float* __restrict__ z, int fin, int fos) {
    int t = blockIdx.x * 256 + threadIdx.x;
    int fout = 1 << fos;
    int r = t >> fos, o = t & (fout - 1);
    if (r >= ROWS) return;
    const float* xr = x + (long)r * fin;
    float acc = 0.f;
    for (int k = 0; k < fin; k++) acc += xr[k] * w[k * fout + o];
    z[((long)r << fos) + o] = acc;
}

// out = act(x@ws + rdeg * neigh + b)
// postagg=1: neigh = agg[r*fout+o]; postagg=0: neigh = agg_row(fin) . wn[:,o]
__global__ void k_sage_mm(const float* __restrict__ x, const float* __restrict__ agg,
                          const float* __restrict__ rdeg,
                          const float* __restrict__ wself, const float* __restrict__ wneigh,
                          const float* __restrict__ bias, float* __restrict__ out,
                          int fin, int fos, int postagg, int relu,
                          int out_stride, int out_off, int transpose) {
    int t = blockIdx.x * 256 + threadIdx.x;
    int fout = 1 << fos;
    int r = t >> fos, o = t & (fout - 1);
    if (r >= ROWS) return;
    const float* xr = x + (long)r * fin;
    float accs = 0.f, accn = 0.f;
    if (postagg) {
        for (int k = 0; k < fin; k++) accs += xr[k] * wself[k * fout + o];
        accn = agg[((long)r << fos) + o];
    } else {
        const float* ar = agg + (long)r * fin;
        for (int k = 0; k < fin; k++) {
            accs += xr[k] * wself[k * fout + o];
            accn += ar[k] * wneigh[k * fout + o];
        }
    }
    int n = r >> 1;
    float v = accs + rdeg[n] * accn + bias[o];
    if (relu) v = fmaxf(v, 0.f);
    long oidx;
    if (transpose) {
        int b = r & 1;
        oidx = (long)b * (NN * 64) + (long)n * 64 + o;
    } else {
        oidx = (long)r * out_stride + out_off + o;
    }
    out[oidx] = v;
}

// concat copy: out[r][off..off+fin) = x[r][0..fin), in float4 units
__global__ void k_copy(const float4* __restrict__ x, float4* __restrict__ out,
                       int cshift, int ostride4, int ooff4) {
    int t = blockIdx.x * 256 + threadIdx.x;
    int total = ROWS << cshift;
    if (t >= total) return;
    int r = t >> cshift, c = t & ((1 << cshift) - 1);
    out[r * ostride4 + ooff4 + c] = x[t];
}

// ---------------- host ----------------

static inline int ilog2i(int x) { int s = 0; while ((1 << s) < x) s++; return s; }

static void sage_layer(const float* x, int fin,
                       const float* wsf, const float* wnf, const float* bias,
                       int fout, int relu, float* outp, int out_stride, int out_off,
                       int transpose, int postagg,
                       float* zbuf, float* aggb, const float* rdeg,
                       const int* src, const int* dst, hipStream_t stream) {
    int fos = ilog2i(fout);
    int mtotal = ROWS << fos;
    if (postagg) {
        k_mm<<<(mtotal + 255) / 256, 256, 0, stream>>>(x, wnf, zbuf, fin, fos);
        int cs = ilog2i(fout * BB / 4);
        hipMemsetAsync(aggb, 0, (size_t)ROWS * fout * 4, stream);
        int etotal = NE << cs;
        k_agg<<<(etotal + 255) / 256, 256, 0, stream>>>((const float4*)zbuf, src, dst, aggb, cs);
        k_sage_mm<<<(mtotal + 255) / 256, 256, 0, stream>>>(
            x, aggb, rdeg, wsf, wnf, bias, outp, fin, fos, 1, relu, out_stride, out_off, transpose);
    } else {
        int cs = ilog2i(fin * BB / 4);
        hipMemsetAsync(aggb, 0, (size_t)ROWS * fin * 4, stream);
        int etotal = NE << cs;
        k_agg<<<(etotal + 255) / 256, 256, 0, stream>>>((const float4*)x, src, dst, aggb, cs);
        k_sage_mm<<<(mtotal + 255) / 256, 256, 0, stream>>>(
            x, aggb, rdeg, wsf, wnf, bias, outp, fin, fos, 0, relu, out_stride, out_off, transpose);
    }
}

extern "C" void kernel_launch(void* const* d_in, const int* in_sizes, int n_in,
                              void* d_out, int out_size, void* d_ws, size_t ws_size,
                              hipStream_t stream) {
    const float* in_feat = (const float*)d_in[0];
    const int* src = (const int*)d_in[1];
    const int* dst = (const int*)d_in[2];
    const float* Ws[6], *Wn[6], *Bi[6];
    for (int i = 0; i < 6; i++) {
        Ws[i] = (const float*)d_in[3 + 3 * i];
        Wn[i] = (const float*)d_in[4 + 3 * i];
        Bi[i] = (const float*)d_in[5 + 3 * i];
    }

    char* ws = (char*)d_ws;
    float* rdeg = (float*)ws;
    size_t off = ((size_t)NN * 4 + 255) & ~(size_t)255;
    float* buf0 = (float*)(ws + off); off += (size_t)ROWS * 128 * 4;
    float* buf1 = (float*)(ws + off); off += (size_t)ROWS * 128 * 4;
    float* aggb = (float*)(ws + off); off += (size_t)ROWS * 64 * 4;
    float* zbuf = (float*)d_out;   // z is consumed before d_out's final write

    hipMemsetAsync(rdeg, 0, (size_t)NN * 4, stream);
    k_deg<<<(NE + 255) / 256, 256, 0, stream>>>(dst, rdeg);
    k_rdeg<<<(NN + 255) / 256, 256, 0, stream>>>(rdeg);
    k_tin<<<(ROWS * 16 + 255) / 256, 256, 0, stream>>>((const float4*)in_feat, (float4*)buf0);

    for (int s = 0; s < 2; s++) {
        int fin = (s == 1);
        // conv1: 64 -> 128, pre-agg, relu        buf0 -> buf1
        sage_layer(buf0, 64, Ws[0], Wn[0], Bi[0], 128, 1, buf1, 128, 0, 0, 0,
                   zbuf, aggb, rdeg, src, dst, stream);
        // conv2: 128 -> 64, post-agg, relu       buf1 -> buf0
        sage_layer(buf1, 128, Ws[1], Wn[1], Bi[1], 64, 1, buf0, 64, 0, 0, 1,
                   zbuf, aggb, rdeg, src, dst, stream);
        // conv3: 64 -> 32, post-agg, relu        buf0 -> buf1
        sage_layer(buf0, 64, Ws[2], Wn[2], Bi[2], 32, 1, buf1, 32, 0, 0, 1,
                   zbuf, aggb, rdeg, src, dst, stream);
        // conv4: 32 -> 32, pre-agg, relu; concat h3   buf1 -> buf0 (stride 64)
        sage_layer(buf1, 32, Ws[3], Wn[3], Bi[3], 32, 1, buf0, 64, 0, 0, 0,
                   zbuf, aggb, rdeg, src, dst, stream);
        k_copy<<<(ROWS * 8 + 255) / 256, 256, 0, stream>>>(
            (const float4*)buf1, (float4*)buf0, 3, 16, 8);
        // conv5: 64 -> 64, pre-agg, relu; concat h4   buf0 -> buf1 (stride 128)
        sage_layer(buf0, 64, Ws[4], Wn[4], Bi[4], 64, 1, buf1, 128, 0, 0, 0,
                   zbuf, aggb, rdeg, src, dst, stream);
        k_copy<<<(ROWS * 16 + 255) / 256, 256, 0, stream>>>(
            (const float4*)buf0, (float4*)buf1, 4, 32, 16);
        // conv6: 128 -> 64, post-agg, no relu    buf1 -> buf0 (or d_out transposed at the end)
        sage_layer(buf1, 128, Ws[5], Wn[5], Bi[5], 64, 0,
                   fin ? (float*)d_out : buf0, 64, 0, fin, 1,
                   zbuf, aggb, rdeg, src, dst, stream);
    }
}

// Round 3
// 2483.327 us; speedup vs baseline: 4.4588x; 4.4588x over previous
//
#include <hip/hip_runtime.h>

#define NN 50000
#define NE 400000
#define BB 2
#define ROWS (NN * BB)   // 100000 feature rows, row r = node*2 + batch

// ---------------- CSR build ----------------

__global__ void k_hist(const int* __restrict__ dst, int* __restrict__ deg) {
    int e = blockIdx.x * 256 + threadIdx.x;
    if (e < NE) atomicAdd(&deg[dst[e]], 1);
}

// single-block exclusive scan over deg -> rowoff, cursor; also rdeg = 1/max(deg,1)
__global__ void k_scan(const int* __restrict__ deg, int* __restrict__ rowoff,
                       int* __restrict__ cursor, float* __restrict__ rdeg) {
    __shared__ int part[1024];
    int t = threadIdx.x;
    const int CH = (NN + 1023) / 1024;
    int base = t * CH;
    int s = 0;
    for (int i = 0; i < CH; i++) {
        int idx = base + i;
        if (idx < NN) s += deg[idx];
    }
    part[t] = s;
    __syncthreads();
    for (int off = 1; off < 1024; off <<= 1) {
        int v = part[t];
        int add = (t >= off) ? part[t - off] : 0;
        __syncthreads();
        part[t] = v + add;
        __syncthreads();
    }
    int run = (t == 0) ? 0 : part[t - 1];
    for (int i = 0; i < CH; i++) {
        int idx = base + i;
        if (idx < NN) {
            int d = deg[idx];
            rowoff[idx] = run;
            cursor[idx] = run;
            rdeg[idx] = 1.0f / fmaxf((float)d, 1.0f);
            run += d;
        }
    }
    if (t == 1023) rowoff[NN] = run;
}

__global__ void k_fill(const int* __restrict__ src, const int* __restrict__ dst,
                       int* __restrict__ cursor, int* __restrict__ csr) {
    int e = blockIdx.x * 256 + threadIdx.x;
    if (e >= NE) return;
    int pos = atomicAdd(&cursor[dst[e]], 1);
    csr[pos] = src[e];
}

// ---------------- layout / aggregation ----------------

// in_feat [B,N,64] -> h [N*B, 64]
__global__ void k_tin(const float4* __restrict__ in, float4* __restrict__ out) {
    int t = blockIdx.x * 256 + threadIdx.x;
    if (t >= ROWS * 16) return;
    int r = t >> 4, c = t & 15;
    int n = r >> 1, b = r & 1;
    out[t] = in[(b * NN + n) * 16 + c];
}

// mean-aggregate: out[n][c] = rdeg[n] * sum_{s in N(n)} x[s][c]   (payload P=1<<ps float4/node)
__global__ void k_gather(const float4* __restrict__ x, const int* __restrict__ csr,
                         const int* __restrict__ rowoff, const float* __restrict__ rdeg,
                         float4* __restrict__ out, int ps) {
    int t = blockIdx.x * 256 + threadIdx.x;
    int n = t >> ps, c = t & ((1 << ps) - 1);
    if (n >= NN) return;
    int beg = rowoff[n], end = rowoff[n + 1];
    float4 acc = {0.f, 0.f, 0.f, 0.f};
    for (int j = beg; j < end; j++) {
        int s = csr[j];
        float4 v = x[(s << ps) + c];
        acc.x += v.x; acc.y += v.y; acc.z += v.z; acc.w += v.w;
    }
    float rd = rdeg[n];
    float4 o = {acc.x * rd, acc.y * rd, acc.z * rd, acc.w * rd};
    out[(n << ps) + c] = o;
}

// ---------------- matmuls (4 outputs / thread) ----------------

// z = x @ w   (x: [ROWS, fin], w: [fin, fout])
__global__ void k_mm4(const float* __restrict__ x, const float* __restrict__ w,
                      float* __restrict__ z, int fin, int fos) {
    int t = blockIdx.x * 256 + threadIdx.x;
    int oqs = fos - 2;
    int r = t >> oqs;
    int o4 = (t & ((1 << oqs) - 1)) << 2;
    if (r >= ROWS) return;
    int fout = 1 << fos;
    const float4* xr = (const float4*)(x + (long)r * fin);
    float4 acc = {0.f, 0.f, 0.f, 0.f};
    for (int k4 = 0; k4 < (fin >> 2); k4++) {
        float4 xv = xr[k4];
        float xa[4] = {xv.x, xv.y, xv.z, xv.w};
        int kb = k4 << 2;
#pragma unroll
        for (int u = 0; u < 4; u++) {
            float4 w4 = *(const float4*)&w[(kb + u) * fout + o4];
            acc.x += xa[u] * w4.x; acc.y += xa[u] * w4.y;
            acc.z += xa[u] * w4.z; acc.w += xa[u] * w4.w;
        }
    }
    *(float4*)&z[((long)r << fos) + o4] = acc;
}

// out = act(x@ws + neigh + b); postagg: neigh = agg row (already mean'd through wn)
// preagg: neigh = (mean'd agg row, fin wide) @ wn
__global__ void k_sage4(const float* __restrict__ x, const float* __restrict__ agg,
                        const float* __restrict__ wself, const float* __restrict__ wneigh,
                        const float* __restrict__ bias, float* __restrict__ out,
                        int fin, int fos, int postagg, int relu,
                        int out_stride, int out_off, int transpose) {
    int t = blockIdx.x * 256 + threadIdx.x;
    int oqs = fos - 2;
    int r = t >> oqs;
    int o4 = (t & ((1 << oqs) - 1)) << 2;
    if (r >= ROWS) return;
    int fout = 1 << fos;
    const float4* xr = (const float4*)(x + (long)r * fin);
    float4 accs = {0.f, 0.f, 0.f, 0.f}, accn = {0.f, 0.f, 0.f, 0.f};
    if (postagg) {
        for (int k4 = 0; k4 < (fin >> 2); k4++) {
            float4 xv = xr[k4];
            float xa[4] = {xv.x, xv.y, xv.z, xv.w};
            int kb = k4 << 2;
#pragma unroll
            for (int u = 0; u < 4; u++) {
                float4 w4 = *(const float4*)&wself[(kb + u) * fout + o4];
                accs.x += xa[u] * w4.x; accs.y += xa[u] * w4.y;
                accs.z += xa[u] * w4.z; accs.w += xa[u] * w4.w;
            }
        }
        accn = *(const float4*)&agg[((long)r << fos) + o4];
    } else {
        const float4* ar = (const float4*)(agg + (long)r * fin);
        for (int k4 = 0; k4 < (fin >> 2); k4++) {
            float4 xv = xr[k4], av = ar[k4];
            float xa[4] = {xv.x, xv.y, xv.z, xv.w};
            float aa[4] = {av.x, av.y, av.z, av.w};
            int kb = k4 << 2;
#pragma unroll
            for (int u = 0; u < 4; u++) {
                float4 w4 = *(const float4*)&wself[(kb + u) * fout + o4];
                float4 n4 = *(const float4*)&wneigh[(kb + u) * fout + o4];
                accs.x += xa[u] * w4.x; accs.y += xa[u] * w4.y;
                accs.z += xa[u] * w4.z; accs.w += xa[u] * w4.w;
                accn.x += aa[u] * n4.x; accn.y += aa[u] * n4.y;
                accn.z += aa[u] * n4.z; accn.w += aa[u] * n4.w;
            }
        }
    }
    float4 b4 = *(const float4*)&bias[o4];
    float4 v = {accs.x + accn.x + b4.x, accs.y + accn.y + b4.y,
                accs.z + accn.z + b4.z, accs.w + accn.w + b4.w};
    if (relu) {
        v.x = fmaxf(v.x, 0.f); v.y = fmaxf(v.y, 0.f);
        v.z = fmaxf(v.z, 0.f); v.w = fmaxf(v.w, 0.f);
    }
    long oidx;
    if (transpose) {
        int n = r >> 1, b = r & 1;
        oidx = (long)b * (NN * 64) + (long)n * 64 + o4;
    } else {
        oidx = (long)r * out_stride + out_off + o4;
    }
    *(float4*)&out[oidx] = v;
}

// concat copy: out[r][ooff4..) = x[r][0..), float4 units
__global__ void k_copy(const float4* __restrict__ x, float4* __restrict__ out,
                       int cshift, int ostride4, int ooff4) {
    int t = blockIdx.x * 256 + threadIdx.x;
    int total = ROWS << cshift;
    if (t >= total) return;
    int r = t >> cshift, c = t & ((1 << cshift) - 1);
    out[r * ostride4 + ooff4 + c] = x[t];
}

// ---------------- host ----------------

static inline int ilog2i(int x) { int s = 0; while ((1 << s) < x) s++; return s; }

static void sage_layer(const float* x, int fin, const float* wsf, const float* wnf,
                       const float* bias, int fout, int relu, float* outp,
                       int out_stride, int out_off, int transpose, int postagg,
                       float* zbuf, float* aggb, const float* rdeg,
                       const int* csr, const int* rowoff, hipStream_t stream) {
    int fos = ilog2i(fout);
    int mt = ROWS << (fos - 2);
    if (postagg) {
        k_mm4<<<(mt + 255) / 256, 256, 0, stream>>>(x, wnf, zbuf, fin, fos);
        int ps = ilog2i(fout * BB / 4);
        int gt = NN << ps;
        k_gather<<<(gt + 255) / 256, 256, 0, stream>>>(
            (const float4*)zbuf, csr, rowoff, rdeg, (float4*)aggb, ps);
        k_sage4<<<(mt + 255) / 256, 256, 0, stream>>>(
            x, aggb, wsf, wnf, bias, outp, fin, fos, 1, relu, out_stride, out_off, transpose);
    } else {
        int ps = ilog2i(fin * BB / 4);
        int gt = NN << ps;
        k_gather<<<(gt + 255) / 256, 256, 0, stream>>>(
            (const float4*)x, csr, rowoff, rdeg, (float4*)aggb, ps);
        k_sage4<<<(mt + 255) / 256, 256, 0, stream>>>(
            x, aggb, wsf, wnf, bias, outp, fin, fos, 0, relu, out_stride, out_off, transpose);
    }
}

extern "C" void kernel_launch(void* const* d_in, const int* in_sizes, int n_in,
                              void* d_out, int out_size, void* d_ws, size_t ws_size,
                              hipStream_t stream) {
    const float* in_feat = (const float*)d_in[0];
    const int* src = (const int*)d_in[1];
    const int* dst = (const int*)d_in[2];
    const float* Ws[6], *Wn[6], *Bi[6];
    for (int i = 0; i < 6; i++) {
        Ws[i] = (const float*)d_in[3 + 3 * i];
        Wn[i] = (const float*)d_in[4 + 3 * i];
        Bi[i] = (const float*)d_in[5 + 3 * i];
    }

    char* ws = (char*)d_ws;
    size_t off = 0;
    auto alloc = [&](size_t bytes) {
        void* p = ws + off;
        off = (off + bytes + 255) & ~(size_t)255;
        return p;
    };
    float* rdeg   = (float*)alloc((size_t)NN * 4);
    int*   deg    = (int*)  alloc((size_t)NN * 4);
    int*   rowoff = (int*)  alloc((size_t)(NN + 1) * 4);
    int*   cursor = (int*)  alloc((size_t)NN * 4);
    int*   csr    = (int*)  alloc((size_t)NE * 4);
    float* buf0   = (float*)alloc((size_t)ROWS * 128 * 4);
    float* buf1   = (float*)alloc((size_t)ROWS * 128 * 4);
    float* aggb   = (float*)alloc((size_t)ROWS * 64 * 4);
    float* zbuf   = (float*)d_out;   // z consumed before d_out's final write

    // CSR build (every call: ws is re-poisoned)
    hipMemsetAsync(deg, 0, (size_t)NN * 4, stream);
    k_hist<<<(NE + 255) / 256, 256, 0, stream>>>(dst, deg);
    k_scan<<<1, 1024, 0, stream>>>(deg, rowoff, cursor, rdeg);
    k_fill<<<(NE + 255) / 256, 256, 0, stream>>>(src, dst, cursor, csr);

    k_tin<<<(ROWS * 16 + 255) / 256, 256, 0, stream>>>((const float4*)in_feat, (float4*)buf0);

    for (int s = 0; s < 2; s++) {
        int last = (s == 1);
        // conv1: 64 -> 128, pre-agg, relu        buf0 -> buf1
        sage_layer(buf0, 64, Ws[0], Wn[0], Bi[0], 128, 1, buf1, 128, 0, 0, 0,
                   zbuf, aggb, rdeg, csr, rowoff, stream);
        // conv2: 128 -> 64, post-agg, relu       buf1 -> buf0
        sage_layer(buf1, 128, Ws[1], Wn[1], Bi[1], 64, 1, buf0, 64, 0, 0, 1,
                   zbuf, aggb, rdeg, csr, rowoff, stream);
        // conv3: 64 -> 32, post-agg, relu        buf0 -> buf1
        sage_layer(buf0, 64, Ws[2], Wn[2], Bi[2], 32, 1, buf1, 32, 0, 0, 1,
                   zbuf, aggb, rdeg, csr, rowoff, stream);
        // conv4: 32 -> 32, pre-agg, relu; concat h3   buf1 -> buf0 (stride 64)
        sage_layer(buf1, 32, Ws[3], Wn[3], Bi[3], 32, 1, buf0, 64, 0, 0, 0,
                   zbuf, aggb, rdeg, csr, rowoff, stream);
        k_copy<<<(ROWS * 8 + 255) / 256, 256, 0, stream>>>(
            (const float4*)buf1, (float4*)buf0, 3, 16, 8);
        // conv5: 64 -> 64, pre-agg, relu; concat h4   buf0 -> buf1 (stride 128)
        sage_layer(buf0, 64, Ws[4], Wn[4], Bi[4], 64, 1, buf1, 128, 0, 0, 0,
                   zbuf, aggb, rdeg, csr, rowoff, stream);
        k_copy<<<(ROWS * 16 + 255) / 256, 256, 0, stream>>>(
            (const float4*)buf0, (float4*)buf1, 4, 32, 16);
        // conv6: 128 -> 64, post-agg, no relu    buf1 -> buf0 (last: d_out transposed)
        sage_layer(buf1, 128, Ws[5], Wn[5], Bi[5], 64, 0,
                   last ? (float*)d_out : buf0, 64, 0, last, 1,
                   zbuf, aggb, rdeg, csr, rowoff, stream);
    }
}

// Round 4
// 1403.906 us; speedup vs baseline: 7.8870x; 1.7689x over previous
//
#include <hip/hip_runtime.h>

#define NN 50000
#define NE 400000
#define BB 2
#define ROWS (NN * BB)   // 100000 feature rows, row r = node*2 + batch

__device__ inline void fma4(float4& a, float s, const float4& w) {
    a.x = fmaf(s, w.x, a.x); a.y = fmaf(s, w.y, a.y);
    a.z = fmaf(s, w.z, a.z); a.w = fmaf(s, w.w, a.w);
}

// ---------------- CSR build ----------------

__global__ void k_hist(const int* __restrict__ dst, int* __restrict__ deg) {
    int e = blockIdx.x * 256 + threadIdx.x;
    if (e < NE) atomicAdd(&deg[dst[e]], 1);
}

__global__ void k_scan(const int* __restrict__ deg, int* __restrict__ rowoff,
                       int* __restrict__ cursor, float* __restrict__ rdeg) {
    __shared__ int part[1024];
    int t = threadIdx.x;
    const int CH = (NN + 1023) / 1024;
    int base = t * CH;
    int s = 0;
    for (int i = 0; i < CH; i++) {
        int idx = base + i;
        if (idx < NN) s += deg[idx];
    }
    part[t] = s;
    __syncthreads();
    for (int off = 1; off < 1024; off <<= 1) {
        int v = part[t];
        int add = (t >= off) ? part[t - off] : 0;
        __syncthreads();
        part[t] = v + add;
        __syncthreads();
    }
    int run = (t == 0) ? 0 : part[t - 1];
    for (int i = 0; i < CH; i++) {
        int idx = base + i;
        if (idx < NN) {
            int d = deg[idx];
            rowoff[idx] = run;
            cursor[idx] = run;
            rdeg[idx] = 1.0f / fmaxf((float)d, 1.0f);
            run += d;
        }
    }
    if (t == 1023) rowoff[NN] = run;
}

__global__ void k_fill(const int* __restrict__ src, const int* __restrict__ dst,
                       int* __restrict__ cursor, int* __restrict__ csr) {
    int e = blockIdx.x * 256 + threadIdx.x;
    if (e >= NE) return;
    int pos = atomicAdd(&cursor[dst[e]], 1);
    csr[pos] = src[e];
}

// ---------------- layout / aggregation ----------------

// in_feat [B,N,64] -> h [N*B, 64]
__global__ void k_tin(const float4* __restrict__ in, float4* __restrict__ out) {
    int t = blockIdx.x * 256 + threadIdx.x;
    if (t >= ROWS * 16) return;
    int r = t >> 4, c = t & 15;
    int n = r >> 1, b = r & 1;
    out[t] = in[(b * NN + n) * 16 + c];
}

// mean-aggregate: out[n][c] = rdeg[n] * sum_{s in N(n)} x[s][c]  (payload 1<<ps float4/node)
__global__ void k_gather(const float4* __restrict__ x, const int* __restrict__ csr,
                         const int* __restrict__ rowoff, const float* __restrict__ rdeg,
                         float4* __restrict__ out, int ps) {
    int t = blockIdx.x * 256 + threadIdx.x;
    int n = t >> ps, c = t & ((1 << ps) - 1);
    if (n >= NN) return;
    int beg = rowoff[n], end = rowoff[n + 1];
    float4 acc = {0.f, 0.f, 0.f, 0.f};
    for (int j = beg; j < end; j++) {
        int s = csr[j];
        float4 v = x[(s << ps) + c];
        acc.x += v.x; acc.y += v.y; acc.z += v.z; acc.w += v.w;
    }
    float rd = rdeg[n];
    float4 o = {acc.x * rd, acc.y * rd, acc.z * rd, acc.w * rd};
    out[(n << ps) + c] = o;
}

// ---------------- tiled GEMM / SAGE transform ----------------
// MODE 0: out = x @ w0                          (no bias, no relu use)
// MODE 1: out = act(x @ w0 + agg @ w1 + b)      (pre-agg: agg is fin-wide mean)
// MODE 2: out = act(x @ w0 + agg + b)           (post-agg: agg is fout-wide)
template<int FIN, int FOUT, int MODE, bool RELU, bool TRANS>
__global__ __launch_bounds__(256) void k_gemm(
    const float* __restrict__ x, const float* __restrict__ agg,
    const float* __restrict__ w0, const float* __restrict__ w1,
    const float* __restrict__ bias, float* __restrict__ out,
    int ostride4, int ooff4)
{
    constexpr int NQ = FOUT / 4;       // col quads
    constexpr int TX = NQ;             // threads across cols (8..32)
    constexpr int TY = 256 / TX;
    constexpr int RPT = 8;             // rows per thread
    constexpr int TM = TY * RPT;       // rows per block
    constexpr int W4 = FIN * FOUT / 4;
    constexpr int NW = (MODE == 1) ? 2 : 1;

    __shared__ float4 wlds[NW * W4];   // max 64 KB (conv1)

    int t = threadIdx.x;
    const float4* w0v = (const float4*)w0;
    for (int i = t; i < W4; i += 256) wlds[i] = w0v[i];
    if (MODE == 1) {
        const float4* w1v = (const float4*)w1;
        for (int i = t; i < W4; i += 256) wlds[W4 + i] = w1v[i];
    }
    __syncthreads();

    int tx = t % TX, ty = t / TX;
    int rbase = blockIdx.x * TM + ty * RPT;

    int rr[RPT];
#pragma unroll
    for (int i = 0; i < RPT; i++) {
        int r = rbase + i;
        rr[i] = r < ROWS ? r : ROWS - 1;
    }

    float4 acc[RPT];
#pragma unroll
    for (int i = 0; i < RPT; i++) acc[i] = make_float4(0.f, 0.f, 0.f, 0.f);

    const float4* xv4 = (const float4*)x;
    const float4* av4 = (const float4*)agg;

    for (int k4 = 0; k4 < FIN / 4; k4++) {
        float4 wq[4], nq[4];
#pragma unroll
        for (int u = 0; u < 4; u++) {
            wq[u] = wlds[(k4 * 4 + u) * NQ + tx];
            if (MODE == 1) nq[u] = wlds[W4 + (k4 * 4 + u) * NQ + tx];
        }
#pragma unroll
        for (int i = 0; i < RPT; i++) {
            float4 xv = xv4[rr[i] * (FIN / 4) + k4];
            fma4(acc[i], xv.x, wq[0]); fma4(acc[i], xv.y, wq[1]);
            fma4(acc[i], xv.z, wq[2]); fma4(acc[i], xv.w, wq[3]);
            if (MODE == 1) {
                float4 av = av4[rr[i] * (FIN / 4) + k4];
                fma4(acc[i], av.x, nq[0]); fma4(acc[i], av.y, nq[1]);
                fma4(acc[i], av.z, nq[2]); fma4(acc[i], av.w, nq[3]);
            }
        }
    }

    float4 b4 = make_float4(0.f, 0.f, 0.f, 0.f);
    if (MODE != 0) b4 = *(const float4*)&bias[tx * 4];

#pragma unroll
    for (int i = 0; i < RPT; i++) {
        int r = rbase + i;
        if (r >= ROWS) continue;
        float4 v = acc[i];
        if (MODE == 2) {
            float4 ag = av4[r * NQ + tx];
            v.x += ag.x; v.y += ag.y; v.z += ag.z; v.w += ag.w;
        }
        if (MODE != 0) { v.x += b4.x; v.y += b4.y; v.z += b4.z; v.w += b4.w; }
        if (RELU) {
            v.x = fmaxf(v.x, 0.f); v.y = fmaxf(v.y, 0.f);
            v.z = fmaxf(v.z, 0.f); v.w = fmaxf(v.w, 0.f);
        }
        int oidx;
        if (TRANS) {                       // FOUT==64 guaranteed here
            int n = r >> 1, b = r & 1;
            oidx = b * (NN * 16) + n * 16 + tx;
        } else {
            oidx = r * ostride4 + ooff4 + tx;
        }
        ((float4*)out)[oidx] = v;
    }
}

// concat copy: out[r][ooff4..) = x[r][0..), float4 units
__global__ void k_copy(const float4* __restrict__ x, float4* __restrict__ out,
                       int cshift, int ostride4, int ooff4) {
    int t = blockIdx.x * 256 + threadIdx.x;
    int total = ROWS << cshift;
    if (t >= total) return;
    int r = t >> cshift, c = t & ((1 << cshift) - 1);
    out[r * ostride4 + ooff4 + c] = x[t];
}

// ---------------- host ----------------

template<int FIN, int FOUT, int MODE, bool RELU, bool TRANS>
static void launch_gemm(const float* x, const float* agg, const float* w0, const float* w1,
                        const float* bias, float* out, int ostride, int ooff,
                        hipStream_t stream) {
    constexpr int TM = (256 / (FOUT / 4)) * 8;
    int nb = (ROWS + TM - 1) / TM;
    k_gemm<FIN, FOUT, MODE, RELU, TRANS><<<nb, 256, 0, stream>>>(
        x, agg, w0, w1, bias, out, ostride / 4, ooff / 4);
}

static void launch_gather(const float* x, const int* csr, const int* rowoff,
                          const float* rdeg, float* aggb, int width, hipStream_t stream) {
    int ps = 0;
    while ((1 << ps) < width * BB / 4) ps++;
    int gt = NN << ps;
    k_gather<<<(gt + 255) / 256, 256, 0, stream>>>(
        (const float4*)x, csr, rowoff, rdeg, (float4*)aggb, ps);
}

extern "C" void kernel_launch(void* const* d_in, const int* in_sizes, int n_in,
                              void* d_out, int out_size, void* d_ws, size_t ws_size,
                              hipStream_t stream) {
    const float* in_feat = (const float*)d_in[0];
    const int* src = (const int*)d_in[1];
    const int* dst = (const int*)d_in[2];
    const float* Ws[6], *Wn[6], *Bi[6];
    for (int i = 0; i < 6; i++) {
        Ws[i] = (const float*)d_in[3 + 3 * i];
        Wn[i] = (const float*)d_in[4 + 3 * i];
        Bi[i] = (const float*)d_in[5 + 3 * i];
    }

    char* ws = (char*)d_ws;
    size_t off = 0;
    auto alloc = [&](size_t bytes) {
        void* p = ws + off;
        off = (off + bytes + 255) & ~(size_t)255;
        return p;
    };
    float* rdeg   = (float*)alloc((size_t)NN * 4);
    int*   deg    = (int*)  alloc((size_t)NN * 4);
    int*   rowoff = (int*)  alloc((size_t)(NN + 1) * 4);
    int*   cursor = (int*)  alloc((size_t)NN * 4);
    int*   csr    = (int*)  alloc((size_t)NE * 4);
    float* buf0   = (float*)alloc((size_t)ROWS * 128 * 4);
    float* buf1   = (float*)alloc((size_t)ROWS * 128 * 4);
    float* aggb   = (float*)alloc((size_t)ROWS * 64 * 4);
    float* zbuf   = (float*)d_out;   // z consumed before d_out's final write

    // CSR build (ws re-poisoned every call)
    hipMemsetAsync(deg, 0, (size_t)NN * 4, stream);
    k_hist<<<(NE + 255) / 256, 256, 0, stream>>>(dst, deg);
    k_scan<<<1, 1024, 0, stream>>>(deg, rowoff, cursor, rdeg);
    k_fill<<<(NE + 255) / 256, 256, 0, stream>>>(src, dst, cursor, csr);

    k_tin<<<(ROWS * 16 + 255) / 256, 256, 0, stream>>>((const float4*)in_feat, (float4*)buf0);

    for (int s = 0; s < 2; s++) {
        int last = (s == 1);

        // conv1: 64 -> 128, pre-agg, relu         buf0 -> buf1 (stride 128)
        launch_gather(buf0, csr, rowoff, rdeg, aggb, 64, stream);
        launch_gemm<64, 128, 1, true, false>(buf0, aggb, Ws[0], Wn[0], Bi[0],
                                             buf1, 128, 0, stream);

        // conv2: 128 -> 64, post-agg, relu        buf1 -> buf0
        launch_gemm<128, 64, 0, false, false>(buf1, nullptr, Wn[1], nullptr, nullptr,
                                              zbuf, 64, 0, stream);
        launch_gather(zbuf, csr, rowoff, rdeg, aggb, 64, stream);
        launch_gemm<128, 64, 2, true, false>(buf1, aggb, Ws[1], nullptr, Bi[1],
                                             buf0, 64, 0, stream);

        // conv3: 64 -> 32, post-agg, relu         buf0 -> buf1
        launch_gemm<64, 32, 0, false, false>(buf0, nullptr, Wn[2], nullptr, nullptr,
                                             zbuf, 32, 0, stream);
        launch_gather(zbuf, csr, rowoff, rdeg, aggb, 32, stream);
        launch_gemm<64, 32, 2, true, false>(buf0, aggb, Ws[2], nullptr, Bi[2],
                                            buf1, 32, 0, stream);

        // conv4: 32 -> 32, pre-agg, relu; concat h3    buf1 -> buf0 (stride 64)
        launch_gather(buf1, csr, rowoff, rdeg, aggb, 32, stream);
        launch_gemm<32, 32, 1, true, false>(buf1, aggb, Ws[3], Wn[3], Bi[3],
                                            buf0, 64, 0, stream);
        k_copy<<<(ROWS * 8 + 255) / 256, 256, 0, stream>>>(
            (const float4*)buf1, (float4*)buf0, 3, 16, 8);

        // conv5: 64 -> 64, pre-agg, relu; concat h4    buf0 -> buf1 (stride 128)
        launch_gather(buf0, csr, rowoff, rdeg, aggb, 64, stream);
        launch_gemm<64, 64, 1, true, false>(buf0, aggb, Ws[4], Wn[4], Bi[4],
                                            buf1, 128, 0, stream);
        k_copy<<<(ROWS * 16 + 255) / 256, 256, 0, stream>>>(
            (const float4*)buf0, (float4*)buf1, 4, 32, 16);

        // conv6: 128 -> 64, post-agg, no relu     buf1 -> buf0 / d_out (transposed)
        launch_gemm<128, 64, 0, false, false>(buf1, nullptr, Wn[5], nullptr, nullptr,
                                              zbuf, 64, 0, stream);
        launch_gather(zbuf, csr, rowoff, rdeg, aggb, 64, stream);
        if (last) {
            launch_gemm<128, 64, 2, false, true>(buf1, aggb, Ws[5], nullptr, Bi[5],
                                                 (float*)d_out, 64, 0, stream);
        } else {
            launch_gemm<128, 64, 2, false, false>(buf1, aggb, Ws[5], nullptr, Bi[5],
                                                  buf0, 64, 0, stream);
        }
    }
}

// Round 5
// 1275.847 us; speedup vs baseline: 8.6786x; 1.1004x over previous
//
#include <hip/hip_runtime.h>

#define NN 50000
#define NE 400000
#define BB 2
#define ROWS (NN * BB)   // 100000 feature rows, row r = node*2 + batch

#define SCAN_CHUNK 1024
#define SCAN_NB ((NN + SCAN_CHUNK - 1) / SCAN_CHUNK)   // 49 (<= 64)

__device__ inline void fma4(float4& a, float s, const float4& w) {
    a.x = fmaf(s, w.x, a.x); a.y = fmaf(s, w.y, a.y);
    a.z = fmaf(s, w.z, a.z); a.w = fmaf(s, w.w, a.w);
}

// ---------------- CSR build ----------------

__global__ void k_hist(const int* __restrict__ dst, int* __restrict__ deg) {
    int e = blockIdx.x * 256 + threadIdx.x;
    if (e < NE) atomicAdd(&deg[dst[e]], 1);
}

// phase 1: per-block (1024 elems) sums
__global__ __launch_bounds__(256) void k_scan1(const int* __restrict__ deg,
                                               int* __restrict__ bsum) {
    int b = blockIdx.x, t = threadIdx.x;
    int base = b * SCAN_CHUNK + t * 4;
    int s = 0;
#pragma unroll
    for (int i = 0; i < 4; i++) {
        int idx = base + i;
        if (idx < NN) s += deg[idx];
    }
    for (int d = 32; d; d >>= 1) s += __shfl_down(s, d);
    __shared__ int ws[4];
    if ((t & 63) == 0) ws[t >> 6] = s;
    __syncthreads();
    if (t == 0) bsum[b] = ws[0] + ws[1] + ws[2] + ws[3];
}

// phase 2: one wave scans the block sums; writes rowoff[NN] (total)
__global__ void k_scan2(const int* __restrict__ bsum, int* __restrict__ boff,
                        int* __restrict__ rowoff_last) {
    int lane = threadIdx.x;   // 64 threads
    int v = (lane < SCAN_NB) ? bsum[lane] : 0;
    int incl = v;
    for (int d = 1; d < 64; d <<= 1) {
        int o = __shfl_up(incl, d);
        if (lane >= d) incl += o;
    }
    if (lane < SCAN_NB) boff[lane] = incl - v;
    if (lane == 63) rowoff_last[0] = incl;
}

// phase 3: block-local rescan + write rowoff/cursor/rdeg
__global__ __launch_bounds__(256) void k_scan3(const int* __restrict__ deg,
                                               const int* __restrict__ boff,
                                               int* __restrict__ rowoff,
                                               int* __restrict__ cursor,
                                               float* __restrict__ rdeg) {
    int b = blockIdx.x, t = threadIdx.x;
    int lane = t & 63, wv = t >> 6;
    int base = b * SCAN_CHUNK + t * 4;
    int dv[4];
    int ts = 0;
#pragma unroll
    for (int i = 0; i < 4; i++) {
        int idx = base + i;
        dv[i] = (idx < NN) ? deg[idx] : 0;
        ts += dv[i];
    }
    int incl = ts;
    for (int d = 1; d < 64; d <<= 1) {
        int o = __shfl_up(incl, d);
        if (lane >= d) incl += o;
    }
    __shared__ int wsum[4];
    if (lane == 63) wsum[wv] = incl;
    __syncthreads();
    int wexc = 0;
    for (int w = 0; w < wv; w++) wexc += wsum[w];
    int run = boff[b] + wexc + (incl - ts);
#pragma unroll
    for (int i = 0; i < 4; i++) {
        int idx = base + i;
        if (idx < NN) {
            rowoff[idx] = run;
            cursor[idx] = run;
            rdeg[idx] = 1.0f / fmaxf((float)dv[i], 1.0f);
            run += dv[i];
        }
    }
}

__global__ void k_fill(const int* __restrict__ src, const int* __restrict__ dst,
                       int* __restrict__ cursor, int* __restrict__ csr) {
    int e = blockIdx.x * 256 + threadIdx.x;
    if (e >= NE) return;
    int pos = atomicAdd(&cursor[dst[e]], 1);
    csr[pos] = src[e];
}

// ---------------- layout / aggregation ----------------

// in_feat [B,N,64] -> h [N*B, 64]
__global__ void k_tin(const float4* __restrict__ in, float4* __restrict__ out) {
    int t = blockIdx.x * 256 + threadIdx.x;
    if (t >= ROWS * 16) return;
    int r = t >> 4, c = t & 15;
    int n = r >> 1, b = r & 1;
    out[t] = in[(b * NN + n) * 16 + c];
}

// mean-aggregate into packed aggb. Per-node payload = 1<<ps float4 (= BB rows of width).
// x addressing: row (s*2+b) has pitch xpitch4 float4, data at +xoff4. w4s = log2(width/4).
__global__ void k_gather(const float4* __restrict__ x, const int* __restrict__ csr,
                         const int* __restrict__ rowoff, const float* __restrict__ rdeg,
                         float4* __restrict__ out, int ps, int w4s, int xpitch4, int xoff4) {
    int t = blockIdx.x * 256 + threadIdx.x;
    int n = t >> ps, c = t & ((1 << ps) - 1);
    if (n >= NN) return;
    int b = c >> w4s, cc = c & ((1 << w4s) - 1);
    int beg = rowoff[n], end = rowoff[n + 1];
    float4 acc = {0.f, 0.f, 0.f, 0.f};
    int addoff = b * xpitch4 + xoff4 + cc;
    for (int j = beg; j < end; j++) {
        int s = csr[j];
        float4 v = x[(s * 2) * xpitch4 + addoff];
        acc.x += v.x; acc.y += v.y; acc.z += v.z; acc.w += v.w;
    }
    float rd = rdeg[n];
    float4 o = {acc.x * rd, acc.y * rd, acc.z * rd, acc.w * rd};
    out[(n << ps) + c] = o;
}

// ---------------- tiled GEMM / SAGE transform ----------------
// MODE 0: out = x @ w0
// MODE 1: out = act(x @ w0 + agg @ w1 + b)   (pre-agg: agg packed fin-wide)
// MODE 2: out = act(x @ w0 + agg + b)        (post-agg: agg packed fout-wide)
template<int FIN, int FOUT, int MODE, bool RELU, bool TRANS>
__global__ __launch_bounds__(256) void k_gemm(
    const float* __restrict__ x, const float* __restrict__ agg,
    const float* __restrict__ w0, const float* __restrict__ w1,
    const float* __restrict__ bias, float* __restrict__ out,
    int xpitch4, int xoff4, int ostride4, int ooff4)
{
    constexpr int NQ = FOUT / 4;       // col quads
    constexpr int TX = NQ;             // threads across cols (8..32)
    constexpr int TY = 256 / TX;
    constexpr int RPT = 8;             // rows per thread
    constexpr int TM = TY * RPT;       // rows per block
    constexpr int W4 = FIN * FOUT / 4;
    constexpr int NW = (MODE == 1) ? 2 : 1;

    __shared__ float4 wlds[NW * W4];   // max 64 KB (conv1)

    int t = threadIdx.x;
    const float4* w0v = (const float4*)w0;
    for (int i = t; i < W4; i += 256) wlds[i] = w0v[i];
    if (MODE == 1) {
        const float4* w1v = (const float4*)w1;
        for (int i = t; i < W4; i += 256) wlds[W4 + i] = w1v[i];
    }
    __syncthreads();

    int tx = t % TX, ty = t / TX;
    int rbase = blockIdx.x * TM + ty * RPT;

    int xb[RPT];
#pragma unroll
    for (int i = 0; i < RPT; i++) {
        int r = rbase + i;
        r = r < ROWS ? r : ROWS - 1;
        xb[i] = r * xpitch4 + xoff4;
    }

    float4 acc[RPT];
#pragma unroll
    for (int i = 0; i < RPT; i++) acc[i] = make_float4(0.f, 0.f, 0.f, 0.f);

    const float4* xv4 = (const float4*)x;
    const float4* av4 = (const float4*)agg;

    for (int k4 = 0; k4 < FIN / 4; k4++) {
        float4 wq[4], nq[4];
#pragma unroll
        for (int u = 0; u < 4; u++) {
            wq[u] = wlds[(k4 * 4 + u) * NQ + tx];
            if (MODE == 1) nq[u] = wlds[W4 + (k4 * 4 + u) * NQ + tx];
        }
#pragma unroll
        for (int i = 0; i < RPT; i++) {
            float4 xv = xv4[xb[i] + k4];
            fma4(acc[i], xv.x, wq[0]); fma4(acc[i], xv.y, wq[1]);
            fma4(acc[i], xv.z, wq[2]); fma4(acc[i], xv.w, wq[3]);
            if (MODE == 1) {
                int r = rbase + i;
                r = r < ROWS ? r : ROWS - 1;
                float4 av = av4[r * (FIN / 4) + k4];
                fma4(acc[i], av.x, nq[0]); fma4(acc[i], av.y, nq[1]);
                fma4(acc[i], av.z, nq[2]); fma4(acc[i], av.w, nq[3]);
            }
        }
    }

    float4 b4 = make_float4(0.f, 0.f, 0.f, 0.f);
    if (MODE != 0) b4 = *(const float4*)&bias[tx * 4];

#pragma unroll
    for (int i = 0; i < RPT; i++) {
        int r = rbase + i;
        if (r >= ROWS) continue;
        float4 v = acc[i];
        if (MODE == 2) {
            float4 ag = av4[r * NQ + tx];
            v.x += ag.x; v.y += ag.y; v.z += ag.z; v.w += ag.w;
        }
        if (MODE != 0) { v.x += b4.x; v.y += b4.y; v.z += b4.z; v.w += b4.w; }
        if (RELU) {
            v.x = fmaxf(v.x, 0.f); v.y = fmaxf(v.y, 0.f);
            v.z = fmaxf(v.z, 0.f); v.w = fmaxf(v.w, 0.f);
        }
        int oidx;
        if (TRANS) {                       // FOUT==64 here
            int n = r >> 1, b = r & 1;
            oidx = b * (NN * 16) + n * 16 + tx;
        } else {
            oidx = r * ostride4 + ooff4 + tx;
        }
        ((float4*)out)[oidx] = v;
    }
}

// ---------------- host ----------------

template<int FIN, int FOUT, int MODE, bool RELU, bool TRANS>
static void launch_gemm(const float* x, const float* agg, const float* w0, const float* w1,
                        const float* bias, float* out, int xpitch4, int xoff4,
                        int ostride4, int ooff4, hipStream_t stream) {
    constexpr int TM = (256 / (FOUT / 4)) * 8;
    int nb = (ROWS + TM - 1) / TM;
    k_gemm<FIN, FOUT, MODE, RELU, TRANS><<<nb, 256, 0, stream>>>(
        x, agg, w0, w1, bias, out, xpitch4, xoff4, ostride4, ooff4);
}

// width in floats; x has row pitch xpitch4 (float4), data at +xoff4
static void launch_gather(const float* x, const int* csr, const int* rowoff,
                          const float* rdeg, float* aggb, int width,
                          int xpitch4, int xoff4, hipStream_t stream) {
    int w4s = 0;
    while ((1 << w4s) < width / 4) w4s++;
    int ps = w4s + 1;   // BB = 2
    int gt = NN << ps;
    k_gather<<<(gt + 255) / 256, 256, 0, stream>>>(
        (const float4*)x, csr, rowoff, rdeg, (float4*)aggb, ps, w4s, xpitch4, xoff4);
}

extern "C" void kernel_launch(void* const* d_in, const int* in_sizes, int n_in,
                              void* d_out, int out_size, void* d_ws, size_t ws_size,
                              hipStream_t stream) {
    const float* in_feat = (const float*)d_in[0];
    const int* src = (const int*)d_in[1];
    const int* dst = (const int*)d_in[2];
    const float* Ws[6], *Wn[6], *Bi[6];
    for (int i = 0; i < 6; i++) {
        Ws[i] = (const float*)d_in[3 + 3 * i];
        Wn[i] = (const float*)d_in[4 + 3 * i];
        Bi[i] = (const float*)d_in[5 + 3 * i];
    }

    char* ws = (char*)d_ws;
    size_t off = 0;
    auto alloc = [&](size_t bytes) {
        void* p = ws + off;
        off = (off + bytes + 255) & ~(size_t)255;
        return p;
    };
    float* rdeg   = (float*)alloc((size_t)NN * 4);
    int*   deg    = (int*)  alloc((size_t)NN * 4);
    int*   rowoff = (int*)  alloc((size_t)(NN + 1) * 4);
    int*   cursor = (int*)  alloc((size_t)NN * 4);
    int*   csr    = (int*)  alloc((size_t)NE * 4);
    int*   bsum   = (int*)  alloc((size_t)SCAN_NB * 4);
    int*   boff   = (int*)  alloc((size_t)SCAN_NB * 4);
    float* bufH   = (float*)alloc((size_t)ROWS * 64 * 4);    // h (step input, 64w)
    float* bufA   = (float*)alloc((size_t)ROWS * 128 * 4);   // h1 (128w)
    float* bufB   = (float*)alloc((size_t)ROWS * 128 * 4);   // h5 concat home [c5|c4|h3]
    float* aggb   = (float*)alloc((size_t)ROWS * 64 * 4);
    float* zbuf   = (float*)d_out;   // z scratch; dead before final d_out write

    // CSR build (ws re-poisoned every call)
    hipMemsetAsync(deg, 0, (size_t)NN * 4, stream);
    k_hist<<<(NE + 255) / 256, 256, 0, stream>>>(dst, deg);
    k_scan1<<<SCAN_NB, 256, 0, stream>>>(deg, bsum);
    k_scan2<<<1, 64, 0, stream>>>(bsum, boff, rowoff + NN);
    k_scan3<<<SCAN_NB, 256, 0, stream>>>(deg, boff, rowoff, cursor, rdeg);
    k_fill<<<(NE + 255) / 256, 256, 0, stream>>>(src, dst, cursor, csr);

    k_tin<<<(ROWS * 16 + 255) / 256, 256, 0, stream>>>((const float4*)in_feat, (float4*)bufH);

    for (int s = 0; s < 2; s++) {
        int last = (s == 1);

        // conv1: 64 -> 128, pre-agg, relu     bufH -> bufA (packed 128w)
        launch_gather(bufH, csr, rowoff, rdeg, aggb, 64, 16, 0, stream);
        launch_gemm<64, 128, 1, true, false>(bufH, aggb, Ws[0], Wn[0], Bi[0],
                                             bufA, 16, 0, 32, 0, stream);

        // conv2: 128 -> 64, post-agg, relu    bufA -> bufH
        launch_gemm<128, 64, 0, false, false>(bufA, nullptr, Wn[1], nullptr, nullptr,
                                              zbuf, 32, 0, 16, 0, stream);
        launch_gather(zbuf, csr, rowoff, rdeg, aggb, 64, 16, 0, stream);
        launch_gemm<128, 64, 2, true, false>(bufA, aggb, Ws[1], nullptr, Bi[1],
                                             bufH, 32, 0, 16, 0, stream);

        // conv3: 64 -> 32, post-agg, relu     bufH -> bufB cols 96..127 (off4 24)
        launch_gemm<64, 32, 0, false, false>(bufH, nullptr, Wn[2], nullptr, nullptr,
                                             zbuf, 16, 0, 8, 0, stream);
        launch_gather(zbuf, csr, rowoff, rdeg, aggb, 32, 8, 0, stream);
        launch_gemm<64, 32, 2, true, false>(bufH, aggb, Ws[2], nullptr, Bi[2],
                                            bufB, 16, 0, 32, 24, stream);

        // conv4: 32 -> 32, pre-agg, relu      bufB(+24) -> bufB cols 64..95 (off4 16)
        launch_gather(bufB, csr, rowoff, rdeg, aggb, 32, 32, 24, stream);
        launch_gemm<32, 32, 1, true, false>(bufB, aggb, Ws[3], Wn[3], Bi[3],
                                            bufB, 32, 24, 32, 16, stream);

        // conv5: 64 -> 64, pre-agg, relu      bufB(+16, h4=64w) -> bufB cols 0..63
        launch_gather(bufB, csr, rowoff, rdeg, aggb, 64, 32, 16, stream);
        launch_gemm<64, 64, 1, true, false>(bufB, aggb, Ws[4], Wn[4], Bi[4],
                                            bufB, 32, 16, 32, 0, stream);

        // conv6: 128 -> 64, post-agg, no relu  bufB(128w) -> bufH / d_out(transposed)
        launch_gemm<128, 64, 0, false, false>(bufB, nullptr, Wn[5], nullptr, nullptr,
                                              zbuf, 32, 0, 16, 0, stream);
        launch_gather(zbuf, csr, rowoff, rdeg, aggb, 64, 16, 0, stream);
        if (last) {
            launch_gemm<128, 64, 2, false, true>(bufB, aggb, Ws[5], nullptr, Bi[5],
                                                 (float*)d_out, 32, 0, 16, 0, stream);
        } else {
            launch_gemm<128, 64, 2, false, false>(bufB, aggb, Ws[5], nullptr, Bi[5],
                                                  bufH, 32, 0, 16, 0, stream);
        }
    }
}

// Round 6
// 1218.614 us; speedup vs baseline: 9.0862x; 1.0470x over previous
//
#include <hip/hip_runtime.h>

#define NN 50000
#define NE 400000
#define BB 2
#define ROWS (NN * BB)   // 100000 feature rows, row r = node*2 + batch

#define SCAN_CHUNK 1024
#define SCAN_NB ((NN + SCAN_CHUNK - 1) / SCAN_CHUNK)   // 49 (<= 64)

__device__ inline void fma4(float4& a, float s, const float4& w) {
    a.x = fmaf(s, w.x, a.x); a.y = fmaf(s, w.y, a.y);
    a.z = fmaf(s, w.z, a.z); a.w = fmaf(s, w.w, a.w);
}
__device__ inline void add4(float4& a, const float4& v) {
    a.x += v.x; a.y += v.y; a.z += v.z; a.w += v.w;
}

// ---------------- CSR build ----------------

__global__ void k_hist(const int* __restrict__ dst, int* __restrict__ deg) {
    int e = blockIdx.x * 256 + threadIdx.x;
    if (e < NE) atomicAdd(&deg[dst[e]], 1);
}

__global__ __launch_bounds__(256) void k_scan1(const int* __restrict__ deg,
                                               int* __restrict__ bsum) {
    int b = blockIdx.x, t = threadIdx.x;
    int base = b * SCAN_CHUNK + t * 4;
    int s = 0;
#pragma unroll
    for (int i = 0; i < 4; i++) {
        int idx = base + i;
        if (idx < NN) s += deg[idx];
    }
    for (int d = 32; d; d >>= 1) s += __shfl_down(s, d);
    __shared__ int ws[4];
    if ((t & 63) == 0) ws[t >> 6] = s;
    __syncthreads();
    if (t == 0) bsum[b] = ws[0] + ws[1] + ws[2] + ws[3];
}

__global__ void k_scan2(const int* __restrict__ bsum, int* __restrict__ boff,
                        int* __restrict__ rowoff_last) {
    int lane = threadIdx.x;   // 64 threads
    int v = (lane < SCAN_NB) ? bsum[lane] : 0;
    int incl = v;
    for (int d = 1; d < 64; d <<= 1) {
        int o = __shfl_up(incl, d);
        if (lane >= d) incl += o;
    }
    if (lane < SCAN_NB) boff[lane] = incl - v;
    if (lane == 63) rowoff_last[0] = incl;
}

__global__ __launch_bounds__(256) void k_scan3(const int* __restrict__ deg,
                                               const int* __restrict__ boff,
                                               int* __restrict__ rowoff,
                                               int* __restrict__ cursor,
                                               float* __restrict__ rdeg) {
    int b = blockIdx.x, t = threadIdx.x;
    int lane = t & 63, wv = t >> 6;
    int base = b * SCAN_CHUNK + t * 4;
    int dv[4];
    int ts = 0;
#pragma unroll
    for (int i = 0; i < 4; i++) {
        int idx = base + i;
        dv[i] = (idx < NN) ? deg[idx] : 0;
        ts += dv[i];
    }
    int incl = ts;
    for (int d = 1; d < 64; d <<= 1) {
        int o = __shfl_up(incl, d);
        if (lane >= d) incl += o;
    }
    __shared__ int wsum[4];
    if (lane == 63) wsum[wv] = incl;
    __syncthreads();
    int wexc = 0;
    for (int w = 0; w < wv; w++) wexc += wsum[w];
    int run = boff[b] + wexc + (incl - ts);
#pragma unroll
    for (int i = 0; i < 4; i++) {
        int idx = base + i;
        if (idx < NN) {
            rowoff[idx] = run;
            cursor[idx] = run;
            rdeg[idx] = 1.0f / fmaxf((float)dv[i], 1.0f);
            run += dv[i];
        }
    }
}

__global__ void k_fill(const int* __restrict__ src, const int* __restrict__ dst,
                       int* __restrict__ cursor, int* __restrict__ csr) {
    int e = blockIdx.x * 256 + threadIdx.x;
    if (e >= NE) return;
    int pos = atomicAdd(&cursor[dst[e]], 1);
    csr[pos] = src[e];
}

// ---------------- layout / aggregation ----------------

// in_feat [B,N,64] -> h [N*B, 64]
__global__ void k_tin(const float4* __restrict__ in, float4* __restrict__ out) {
    int t = blockIdx.x * 256 + threadIdx.x;
    if (t >= ROWS * 16) return;
    int r = t >> 4, c = t & 15;
    int n = r >> 1, b = r & 1;
    out[t] = in[(b * NN + n) * 16 + c];
}

// mean-aggregate. Thread (n, c): c = b*(width/4) + cc. Reads x rows (2s+b) with pitch
// xpitch4 at +xoff4; writes out[(2n+b)*opitch4 + ooff4 + cc]. 2x edge-unrolled.
__global__ void k_gather(const float4* __restrict__ x, const int* __restrict__ csr,
                         const int* __restrict__ rowoff, const float* __restrict__ rdeg,
                         float4* __restrict__ out, int ps, int w4s,
                         int xpitch4, int xoff4, int opitch4, int ooff4) {
    int t = blockIdx.x * 256 + threadIdx.x;
    int n = t >> ps, c = t & ((1 << ps) - 1);
    if (n >= NN) return;
    int b = c >> w4s, cc = c & ((1 << w4s) - 1);
    int beg = rowoff[n], end = rowoff[n + 1];
    int addoff = b * xpitch4 + xoff4 + cc;
    int xp2 = 2 * xpitch4;
    float4 a0 = {0.f, 0.f, 0.f, 0.f}, a1 = {0.f, 0.f, 0.f, 0.f};
    int j = beg;
    for (; j + 2 <= end; j += 2) {
        int s0 = csr[j], s1 = csr[j + 1];
        float4 v0 = x[s0 * xp2 + addoff];
        float4 v1 = x[s1 * xp2 + addoff];
        add4(a0, v0); add4(a1, v1);
    }
    if (j < end) {
        int s0 = csr[j];
        add4(a0, x[s0 * xp2 + addoff]);
    }
    float rd = rdeg[n];
    float4 o = {(a0.x + a1.x) * rd, (a0.y + a1.y) * rd,
                (a0.z + a1.z) * rd, (a0.w + a1.w) * rd};
    out[(n * 2 + b) * opitch4 + ooff4 + cc] = o;
}

// ---------------- tiled GEMM / SAGE transform ----------------
// MODE 0: out = x @ w0
// MODE 1: out = act(x @ w0 + agg @ w1 + b)   (agg row: r*apitch4 + aoff4 + k4)
// MODE 2: out = act(x @ w0 + agg + b)        (agg row: r*apitch4 + aoff4 + tx)
template<int FIN, int FOUT, int MODE, bool RELU, bool TRANS, int RPT>
__global__ __launch_bounds__(256) void k_gemm(
    const float* __restrict__ x, const float* __restrict__ agg,
    const float* __restrict__ w0, const float* __restrict__ w1,
    const float* __restrict__ bias, float* __restrict__ out,
    int xpitch4, int xoff4, int apitch4, int aoff4, int ostride4, int ooff4)
{
    constexpr int NQ = FOUT / 4;       // col quads
    constexpr int TX = NQ;             // threads across cols (8..32)
    constexpr int TY = 256 / TX;
    constexpr int TM = TY * RPT;       // rows per block
    constexpr int W4 = FIN * FOUT / 4;
    constexpr int NW = (MODE == 1) ? 2 : 1;

    __shared__ float4 wlds[NW * W4];   // max 64 KB (conv1)

    int t = threadIdx.x;
    const float4* w0v = (const float4*)w0;
    for (int i = t; i < W4; i += 256) wlds[i] = w0v[i];
    if (MODE == 1) {
        const float4* w1v = (const float4*)w1;
        for (int i = t; i < W4; i += 256) wlds[W4 + i] = w1v[i];
    }
    __syncthreads();

    int tx = t % TX, ty = t / TX;
    int rbase = blockIdx.x * TM + ty * RPT;

    int xb[RPT], ab[RPT];
#pragma unroll
    for (int i = 0; i < RPT; i++) {
        int r = rbase + i;
        r = r < ROWS ? r : ROWS - 1;
        xb[i] = r * xpitch4 + xoff4;
        ab[i] = r * apitch4 + aoff4;
    }

    float4 acc[RPT];
#pragma unroll
    for (int i = 0; i < RPT; i++) acc[i] = make_float4(0.f, 0.f, 0.f, 0.f);

    const float4* xv4 = (const float4*)x;
    const float4* av4 = (const float4*)agg;

    for (int k4 = 0; k4 < FIN / 4; k4++) {
        float4 wq[4], nq[4];
#pragma unroll
        for (int u = 0; u < 4; u++) {
            wq[u] = wlds[(k4 * 4 + u) * NQ + tx];
            if (MODE == 1) nq[u] = wlds[W4 + (k4 * 4 + u) * NQ + tx];
        }
#pragma unroll
        for (int i = 0; i < RPT; i++) {
            float4 xv = xv4[xb[i] + k4];
            fma4(acc[i], xv.x, wq[0]); fma4(acc[i], xv.y, wq[1]);
            fma4(acc[i], xv.z, wq[2]); fma4(acc[i], xv.w, wq[3]);
            if (MODE == 1) {
                float4 av = av4[ab[i] + k4];
                fma4(acc[i], av.x, nq[0]); fma4(acc[i], av.y, nq[1]);
                fma4(acc[i], av.z, nq[2]); fma4(acc[i], av.w, nq[3]);
            }
        }
    }

    float4 b4 = make_float4(0.f, 0.f, 0.f, 0.f);
    if (MODE != 0) b4 = *(const float4*)&bias[tx * 4];

#pragma unroll
    for (int i = 0; i < RPT; i++) {
        int r = rbase + i;
        if (r >= ROWS) continue;
        float4 v = acc[i];
        if (MODE == 2) {
            float4 ag = av4[ab[i] + tx];
            add4(v, ag);
        }
        if (MODE != 0) add4(v, b4);
        if (RELU) {
            v.x = fmaxf(v.x, 0.f); v.y = fmaxf(v.y, 0.f);
            v.z = fmaxf(v.z, 0.f); v.w = fmaxf(v.w, 0.f);
        }
        int oidx;
        if (TRANS) {                       // FOUT==64 here
            int n = r >> 1, b = r & 1;
            oidx = b * (NN * 16) + n * 16 + tx;
        } else {
            oidx = r * ostride4 + ooff4 + tx;
        }
        ((float4*)out)[oidx] = v;
    }
}

// ---------------- host ----------------

template<int FIN, int FOUT, int MODE, bool RELU, bool TRANS, int RPT = 8>
static void launch_gemm(const float* x, const float* agg, const float* w0, const float* w1,
                        const float* bias, float* out, int xpitch4, int xoff4,
                        int apitch4, int aoff4, int ostride4, int ooff4,
                        hipStream_t stream) {
    constexpr int TM = (256 / (FOUT / 4)) * RPT;
    int nb = (ROWS + TM - 1) / TM;
    k_gemm<FIN, FOUT, MODE, RELU, TRANS, RPT><<<nb, 256, 0, stream>>>(
        x, agg, w0, w1, bias, out, xpitch4, xoff4, apitch4, aoff4, ostride4, ooff4);
}

// width in floats
static void launch_gather(const float* x, const int* csr, const int* rowoff,
                          const float* rdeg, float* aggb, int width,
                          int xpitch4, int xoff4, int opitch4, int ooff4,
                          hipStream_t stream) {
    int w4s = 0;
    while ((1 << w4s) < width / 4) w4s++;
    int ps = w4s + 1;   // BB = 2
    int gt = NN << ps;
    k_gather<<<(gt + 255) / 256, 256, 0, stream>>>(
        (const float4*)x, csr, rowoff, rdeg, (float4*)aggb, ps, w4s,
        xpitch4, xoff4, opitch4, ooff4);
}

extern "C" void kernel_launch(void* const* d_in, const int* in_sizes, int n_in,
                              void* d_out, int out_size, void* d_ws, size_t ws_size,
                              hipStream_t stream) {
    const float* in_feat = (const float*)d_in[0];
    const int* src = (const int*)d_in[1];
    const int* dst = (const int*)d_in[2];
    const float* Ws[6], *Wn[6], *Bi[6];
    for (int i = 0; i < 6; i++) {
        Ws[i] = (const float*)d_in[3 + 3 * i];
        Wn[i] = (const float*)d_in[4 + 3 * i];
        Bi[i] = (const float*)d_in[5 + 3 * i];
    }

    char* ws = (char*)d_ws;
    size_t off = 0;
    auto alloc = [&](size_t bytes) {
        void* p = ws + off;
        off = (off + bytes + 255) & ~(size_t)255;
        return p;
    };
    float* rdeg   = (float*)alloc((size_t)NN * 4);
    int*   deg    = (int*)  alloc((size_t)NN * 4);
    int*   rowoff = (int*)  alloc((size_t)(NN + 1) * 4);
    int*   cursor = (int*)  alloc((size_t)NN * 4);
    int*   csr    = (int*)  alloc((size_t)NE * 4);
    int*   bsum   = (int*)  alloc((size_t)SCAN_NB * 4);
    int*   boff   = (int*)  alloc((size_t)SCAN_NB * 4);
    float* bufH   = (float*)alloc((size_t)ROWS * 64 * 4);    // h (step input, 64w)
    float* bufA   = (float*)alloc((size_t)ROWS * 128 * 4);   // h1 (128w)
    float* bufB   = (float*)alloc((size_t)ROWS * 128 * 4);   // h5 concat home [c5|c4|h3]
    float* aggb   = (float*)alloc((size_t)ROWS * 64 * 4);    // packed agg, 64w layout
    float* zbuf   = (float*)d_out;   // z scratch; dead before final d_out write

    // CSR build (ws re-poisoned every call)
    hipMemsetAsync(deg, 0, (size_t)NN * 4, stream);
    k_hist<<<(NE + 255) / 256, 256, 0, stream>>>(dst, deg);
    k_scan1<<<SCAN_NB, 256, 0, stream>>>(deg, bsum);
    k_scan2<<<1, 64, 0, stream>>>(bsum, boff, rowoff + NN);
    k_scan3<<<SCAN_NB, 256, 0, stream>>>(deg, boff, rowoff, cursor, rdeg);
    k_fill<<<(NE + 255) / 256, 256, 0, stream>>>(src, dst, cursor, csr);

    k_tin<<<(ROWS * 16 + 255) / 256, 256, 0, stream>>>((const float4*)in_feat, (float4*)bufH);

    for (int s = 0; s < 2; s++) {
        int last = (s == 1);

        // conv1: 64 -> 128, pre-agg, relu     bufH -> bufA (packed 128w); RPT=16
        launch_gather(bufH, csr, rowoff, rdeg, aggb, 64, 16, 0, 16, 0, stream);
        launch_gemm<64, 128, 1, true, false, 16>(bufH, aggb, Ws[0], Wn[0], Bi[0],
                                                 bufA, 16, 0, 16, 0, 32, 0, stream);

        // conv2: 128 -> 64, post-agg, relu    bufA -> bufH
        launch_gemm<128, 64, 0, false, false>(bufA, nullptr, Wn[1], nullptr, nullptr,
                                              zbuf, 32, 0, 0, 0, 16, 0, stream);
        launch_gather(zbuf, csr, rowoff, rdeg, aggb, 64, 16, 0, 16, 0, stream);
        launch_gemm<128, 64, 2, true, false>(bufA, aggb, Ws[1], nullptr, Bi[1],
                                             bufH, 32, 0, 16, 0, 16, 0, stream);

        // conv3: 64 -> 32, post-agg, relu     bufH -> bufB cols 96..127 (off4 24)
        launch_gemm<64, 32, 0, false, false>(bufH, nullptr, Wn[2], nullptr, nullptr,
                                             zbuf, 16, 0, 0, 0, 8, 0, stream);
        launch_gather(zbuf, csr, rowoff, rdeg, aggb, 32, 8, 0, 8, 0, stream);
        launch_gemm<64, 32, 2, true, false>(bufH, aggb, Ws[2], nullptr, Bi[2],
                                            bufB, 16, 0, 8, 0, 32, 24, stream);

        // conv4: 32 -> 32, pre-agg, relu      bufB(+24 h3) -> bufB cols 64..95 (off4 16)
        // h3-agg goes to slots 8..15 of 64w agg (reused by conv5)
        launch_gather(bufB, csr, rowoff, rdeg, aggb, 32, 32, 24, 16, 8, stream);
        launch_gemm<32, 32, 1, true, false>(bufB, aggb, Ws[3], Wn[3], Bi[3],
                                            bufB, 32, 24, 16, 8, 32, 16, stream);

        // conv5: 64 -> 64, pre-agg, relu      bufB(+16 h4) -> bufB cols 0..63
        // gather only c4 (cols 64..95) into slots 0..7; slots 8..15 = h3-agg from conv4
        launch_gather(bufB, csr, rowoff, rdeg, aggb, 32, 32, 16, 16, 0, stream);
        launch_gemm<64, 64, 1, true, false>(bufB, aggb, Ws[4], Wn[4], Bi[4],
                                            bufB, 32, 16, 16, 0, 32, 0, stream);

        // conv6: 128 -> 64, post-agg, no relu  bufB(128w) -> bufH / d_out(transposed)
        launch_gemm<128, 64, 0, false, false>(bufB, nullptr, Wn[5], nullptr, nullptr,
                                              zbuf, 32, 0, 0, 0, 16, 0, stream);
        launch_gather(zbuf, csr, rowoff, rdeg, aggb, 64, 16, 0, 16, 0, stream);
        if (last) {
            launch_gemm<128, 64, 2, false, true>(bufB, aggb, Ws[5], nullptr, Bi[5],
                                                 (float*)d_out, 32, 0, 16, 0, 16, 0, stream);
        } else {
            launch_gemm<128, 64, 2, false, false>(bufB, aggb, Ws[5], nullptr, Bi[5],
                                                  bufH, 32, 0, 16, 0, 16, 0, stream);
        }
    }
}

// Round 7
// 1115.830 us; speedup vs baseline: 9.9232x; 1.0921x over previous
//
#include <hip/hip_runtime.h>

#define NN 50000
#define NE 400000
#define BB 2
#define ROWS (NN * BB)   // 100000 feature rows, row r = node*2 + batch

#define SCAN_CHUNK 1024
#define SCAN_NB ((NN + SCAN_CHUNK - 1) / SCAN_CHUNK)   // 49 (<= 64)

__device__ inline void fma4(float4& a, float s, const float4& w) {
    a.x = fmaf(s, w.x, a.x); a.y = fmaf(s, w.y, a.y);
    a.z = fmaf(s, w.z, a.z); a.w = fmaf(s, w.w, a.w);
}
__device__ inline void add4(float4& a, const float4& v) {
    a.x += v.x; a.y += v.y; a.z += v.z; a.w += v.w;
}

// ---------------- CSR build ----------------

__global__ void k_hist(const int* __restrict__ dst, int* __restrict__ deg) {
    int e = blockIdx.x * 256 + threadIdx.x;
    if (e < NE) atomicAdd(&deg[dst[e]], 1);
}

__global__ __launch_bounds__(256) void k_scan1(const int* __restrict__ deg,
                                               int* __restrict__ bsum) {
    int b = blockIdx.x, t = threadIdx.x;
    int base = b * SCAN_CHUNK + t * 4;
    int s = 0;
#pragma unroll
    for (int i = 0; i < 4; i++) {
        int idx = base + i;
        if (idx < NN) s += deg[idx];
    }
    for (int d = 32; d; d >>= 1) s += __shfl_down(s, d);
    __shared__ int ws[4];
    if ((t & 63) == 0) ws[t >> 6] = s;
    __syncthreads();
    if (t == 0) bsum[b] = ws[0] + ws[1] + ws[2] + ws[3];
}

__global__ void k_scan2(const int* __restrict__ bsum, int* __restrict__ boff,
                        int* __restrict__ rowoff_last) {
    int lane = threadIdx.x;   // 64 threads
    int v = (lane < SCAN_NB) ? bsum[lane] : 0;
    int incl = v;
    for (int d = 1; d < 64; d <<= 1) {
        int o = __shfl_up(incl, d);
        if (lane >= d) incl += o;
    }
    if (lane < SCAN_NB) boff[lane] = incl - v;
    if (lane == 63) rowoff_last[0] = incl;
}

__global__ __launch_bounds__(256) void k_scan3(const int* __restrict__ deg,
                                               const int* __restrict__ boff,
                                               int* __restrict__ rowoff,
                                               int* __restrict__ cursor,
                                               float* __restrict__ rdeg) {
    int b = blockIdx.x, t = threadIdx.x;
    int lane = t & 63, wv = t >> 6;
    int base = b * SCAN_CHUNK + t * 4;
    int dv[4];
    int ts = 0;
#pragma unroll
    for (int i = 0; i < 4; i++) {
        int idx = base + i;
        dv[i] = (idx < NN) ? deg[idx] : 0;
        ts += dv[i];
    }
    int incl = ts;
    for (int d = 1; d < 64; d <<= 1) {
        int o = __shfl_up(incl, d);
        if (lane >= d) incl += o;
    }
    __shared__ int wsum[4];
    if (lane == 63) wsum[wv] = incl;
    __syncthreads();
    int wexc = 0;
    for (int w = 0; w < wv; w++) wexc += wsum[w];
    int run = boff[b] + wexc + (incl - ts);
#pragma unroll
    for (int i = 0; i < 4; i++) {
        int idx = base + i;
        if (idx < NN) {
            rowoff[idx] = run;
            cursor[idx] = run;
            rdeg[idx] = 1.0f / fmaxf((float)dv[i], 1.0f);
            run += dv[i];
        }
    }
}

__global__ void k_fill(const int* __restrict__ src, const int* __restrict__ dst,
                       int* __restrict__ cursor, int* __restrict__ csr) {
    int e = blockIdx.x * 256 + threadIdx.x;
    if (e >= NE) return;
    int pos = atomicAdd(&cursor[dst[e]], 1);
    csr[pos] = src[e];
}

// ---------------- layout / aggregation ----------------

// in_feat [B,N,64] -> h [N*B, 64]
__global__ void k_tin(const float4* __restrict__ in, float4* __restrict__ out) {
    int t = blockIdx.x * 256 + threadIdx.x;
    if (t >= ROWS * 16) return;
    int r = t >> 4, c = t & 15;
    int n = r >> 1, b = r & 1;
    out[t] = in[(b * NN + n) * 16 + c];
}

// mean-aggregate. Thread owns quad `tid` of BOTH batch rows of node n.
// TPN = width/4 threads per node (w4s = log2). 4x edge unroll, 8 loads in flight.
__global__ void k_gather(const float4* __restrict__ x, const int* __restrict__ csr,
                         const int* __restrict__ rowoff, const float* __restrict__ rdeg,
                         float4* __restrict__ out, int w4s,
                         int xp4, int xo4, int op4, int oo4) {
    int t = blockIdx.x * 256 + threadIdx.x;
    int n = t >> w4s, tid = t & ((1 << w4s) - 1);
    if (n >= NN) return;
    int beg = rowoff[n], end = rowoff[n + 1];
    int a0 = xo4 + tid;
    int xp2 = 2 * xp4;
    float4 c00 = {0.f,0.f,0.f,0.f}, c01 = {0.f,0.f,0.f,0.f};
    float4 c10 = {0.f,0.f,0.f,0.f}, c11 = {0.f,0.f,0.f,0.f};
    int j = beg;
    for (; j + 4 <= end; j += 4) {
        int s0 = csr[j], s1 = csr[j+1], s2 = csr[j+2], s3 = csr[j+3];
        int b0 = s0 * xp2 + a0, b1 = s1 * xp2 + a0;
        int b2 = s2 * xp2 + a0, b3 = s3 * xp2 + a0;
        float4 p0 = x[b0], q0 = x[b0 + xp4];
        float4 p1 = x[b1], q1 = x[b1 + xp4];
        float4 p2 = x[b2], q2 = x[b2 + xp4];
        float4 p3 = x[b3], q3 = x[b3 + xp4];
        add4(c00, p0); add4(c10, q0); add4(c01, p1); add4(c11, q1);
        add4(c00, p2); add4(c10, q2); add4(c01, p3); add4(c11, q3);
    }
    for (; j < end; j++) {
        int s = csr[j];
        int b = s * xp2 + a0;
        add4(c00, x[b]); add4(c10, x[b + xp4]);
    }
    float rd = rdeg[n];
    float4 o0 = {(c00.x+c01.x)*rd, (c00.y+c01.y)*rd, (c00.z+c01.z)*rd, (c00.w+c01.w)*rd};
    float4 o1 = {(c10.x+c11.x)*rd, (c10.y+c11.y)*rd, (c10.z+c11.z)*rd, (c10.w+c11.w)*rd};
    out[(2*n)     * op4 + oo4 + tid] = o0;
    out[(2*n + 1) * op4 + oo4 + tid] = o1;
}

// ---------------- tiled GEMM / SAGE transform ----------------
// MODE 0: out = x @ w0
// MODE 1: out = act(x @ w0 + agg @ w1 + b)   (agg row: r*apitch4 + aoff4 + k4)
// MODE 2: out = act(x @ w0 + agg + b)        (agg row: r*apitch4 + aoff4 + quad)
// Each thread: RPT rows x NCQ column-quads (quads tx + j*TX).
template<int FIN, int FOUT, int MODE, bool RELU, bool TRANS, int RPT, int NCQ>
__global__ __launch_bounds__(256) void k_gemm(
    const float* __restrict__ x, const float* __restrict__ agg,
    const float* __restrict__ w0, const float* __restrict__ w1,
    const float* __restrict__ bias, float* __restrict__ out,
    int xpitch4, int xoff4, int apitch4, int aoff4, int ostride4, int ooff4)
{
    constexpr int NQ = FOUT / 4;       // total col quads
    constexpr int TX = NQ / NCQ;       // threads across cols
    constexpr int TY = 256 / TX;
    constexpr int TM = TY * RPT;       // rows per block
    constexpr int W4 = FIN * FOUT / 4;
    constexpr int NW = (MODE == 1) ? 2 : 1;

    __shared__ float4 wlds[NW * W4];   // max 64 KB (conv1)

    int t = threadIdx.x;
    const float4* w0v = (const float4*)w0;
    for (int i = t; i < W4; i += 256) wlds[i] = w0v[i];
    if (MODE == 1) {
        const float4* w1v = (const float4*)w1;
        for (int i = t; i < W4; i += 256) wlds[W4 + i] = w1v[i];
    }
    __syncthreads();

    int tx = t % TX, ty = t / TX;
    int rbase = blockIdx.x * TM + ty * RPT;

    int xb[RPT], ab[RPT];
#pragma unroll
    for (int i = 0; i < RPT; i++) {
        int r = rbase + i;
        r = r < ROWS ? r : ROWS - 1;
        xb[i] = r * xpitch4 + xoff4;
        ab[i] = r * apitch4 + aoff4;
    }

    float4 acc[RPT][NCQ];
#pragma unroll
    for (int i = 0; i < RPT; i++)
#pragma unroll
        for (int j = 0; j < NCQ; j++) acc[i][j] = make_float4(0.f, 0.f, 0.f, 0.f);

    const float4* xv4 = (const float4*)x;
    const float4* av4 = (const float4*)agg;

    for (int k4 = 0; k4 < FIN / 4; k4++) {
        float4 wq[4][NCQ], nq[4][NCQ];
#pragma unroll
        for (int u = 0; u < 4; u++)
#pragma unroll
            for (int j = 0; j < NCQ; j++) {
                wq[u][j] = wlds[(k4 * 4 + u) * NQ + tx + j * TX];
                if (MODE == 1) nq[u][j] = wlds[W4 + (k4 * 4 + u) * NQ + tx + j * TX];
            }
#pragma unroll
        for (int i = 0; i < RPT; i++) {
            float4 xv = xv4[xb[i] + k4];
#pragma unroll
            for (int j = 0; j < NCQ; j++) {
                fma4(acc[i][j], xv.x, wq[0][j]); fma4(acc[i][j], xv.y, wq[1][j]);
                fma4(acc[i][j], xv.z, wq[2][j]); fma4(acc[i][j], xv.w, wq[3][j]);
            }
            if (MODE == 1) {
                float4 av = av4[ab[i] + k4];
#pragma unroll
                for (int j = 0; j < NCQ; j++) {
                    fma4(acc[i][j], av.x, nq[0][j]); fma4(acc[i][j], av.y, nq[1][j]);
                    fma4(acc[i][j], av.z, nq[2][j]); fma4(acc[i][j], av.w, nq[3][j]);
                }
            }
        }
    }

    float4 b4[NCQ];
#pragma unroll
    for (int j = 0; j < NCQ; j++) {
        b4[j] = make_float4(0.f, 0.f, 0.f, 0.f);
        if (MODE != 0) b4[j] = *(const float4*)&bias[(tx + j * TX) * 4];
    }

#pragma unroll
    for (int i = 0; i < RPT; i++) {
        int r = rbase + i;
        if (r >= ROWS) continue;
#pragma unroll
        for (int j = 0; j < NCQ; j++) {
            int q = tx + j * TX;
            float4 v = acc[i][j];
            if (MODE == 2) {
                float4 ag = av4[ab[i] + q];
                add4(v, ag);
            }
            if (MODE != 0) add4(v, b4[j]);
            if (RELU) {
                v.x = fmaxf(v.x, 0.f); v.y = fmaxf(v.y, 0.f);
                v.z = fmaxf(v.z, 0.f); v.w = fmaxf(v.w, 0.f);
            }
            int oidx;
            if (TRANS) {                       // FOUT==64 here
                int n = r >> 1, b = r & 1;
                oidx = b * (NN * 16) + n * 16 + q;
            } else {
                oidx = r * ostride4 + ooff4 + q;
            }
            ((float4*)out)[oidx] = v;
        }
    }
}

// ---------------- host ----------------

template<int FIN, int FOUT, int MODE, bool RELU, bool TRANS, int RPT = 8, int NCQ = 1>
static void launch_gemm(const float* x, const float* agg, const float* w0, const float* w1,
                        const float* bias, float* out, int xpitch4, int xoff4,
                        int apitch4, int aoff4, int ostride4, int ooff4,
                        hipStream_t stream) {
    constexpr int TM = (256 / (FOUT / 4 / NCQ)) * RPT;
    int nb = (ROWS + TM - 1) / TM;
    k_gemm<FIN, FOUT, MODE, RELU, TRANS, RPT, NCQ><<<nb, 256, 0, stream>>>(
        x, agg, w0, w1, bias, out, xpitch4, xoff4, apitch4, aoff4, ostride4, ooff4);
}

// width in floats
static void launch_gather(const float* x, const int* csr, const int* rowoff,
                          const float* rdeg, float* aggb, int width,
                          int xpitch4, int xoff4, int opitch4, int ooff4,
                          hipStream_t stream) {
    int w4s = 0;
    while ((1 << w4s) < width / 4) w4s++;
    int gt = NN << w4s;
    k_gather<<<(gt + 255) / 256, 256, 0, stream>>>(
        (const float4*)x, csr, rowoff, rdeg, (float4*)aggb, w4s,
        xpitch4, xoff4, opitch4, ooff4);
}

extern "C" void kernel_launch(void* const* d_in, const int* in_sizes, int n_in,
                              void* d_out, int out_size, void* d_ws, size_t ws_size,
                              hipStream_t stream) {
    const float* in_feat = (const float*)d_in[0];
    const int* src = (const int*)d_in[1];
    const int* dst = (const int*)d_in[2];
    const float* Ws[6], *Wn[6], *Bi[6];
    for (int i = 0; i < 6; i++) {
        Ws[i] = (const float*)d_in[3 + 3 * i];
        Wn[i] = (const float*)d_in[4 + 3 * i];
        Bi[i] = (const float*)d_in[5 + 3 * i];
    }

    char* ws = (char*)d_ws;
    size_t off = 0;
    auto alloc = [&](size_t bytes) {
        void* p = ws + off;
        off = (off + bytes + 255) & ~(size_t)255;
        return p;
    };
    float* rdeg   = (float*)alloc((size_t)NN * 4);
    int*   deg    = (int*)  alloc((size_t)NN * 4);
    int*   rowoff = (int*)  alloc((size_t)(NN + 1) * 4);
    int*   cursor = (int*)  alloc((size_t)NN * 4);
    int*   csr    = (int*)  alloc((size_t)NE * 4);
    int*   bsum   = (int*)  alloc((size_t)SCAN_NB * 4);
    int*   boff   = (int*)  alloc((size_t)SCAN_NB * 4);
    float* bufH   = (float*)alloc((size_t)ROWS * 64 * 4);    // h (step input, 64w)
    float* bufA   = (float*)alloc((size_t)ROWS * 128 * 4);   // h1 (128w)
    float* bufB   = (float*)alloc((size_t)ROWS * 128 * 4);   // h5 concat home [c5|c4|h3]
    float* aggb   = (float*)alloc((size_t)ROWS * 64 * 4);    // packed agg, 64w layout
    float* zbuf   = (float*)d_out;   // z scratch; dead before final d_out write

    // CSR build (ws re-poisoned every call)
    hipMemsetAsync(deg, 0, (size_t)NN * 4, stream);
    k_hist<<<(NE + 255) / 256, 256, 0, stream>>>(dst, deg);
    k_scan1<<<SCAN_NB, 256, 0, stream>>>(deg, bsum);
    k_scan2<<<1, 64, 0, stream>>>(bsum, boff, rowoff + NN);
    k_scan3<<<SCAN_NB, 256, 0, stream>>>(deg, boff, rowoff, cursor, rdeg);
    k_fill<<<(NE + 255) / 256, 256, 0, stream>>>(src, dst, cursor, csr);

    k_tin<<<(ROWS * 16 + 255) / 256, 256, 0, stream>>>((const float4*)in_feat, (float4*)bufH);

    for (int s = 0; s < 2; s++) {
        int last = (s == 1);

        // conv1: 64 -> 128, pre-agg, relu     bufH -> bufA (packed 128w)
        launch_gather(bufH, csr, rowoff, rdeg, aggb, 64, 16, 0, 16, 0, stream);
        launch_gemm<64, 128, 1, true, false, 8, 2>(bufH, aggb, Ws[0], Wn[0], Bi[0],
                                                   bufA, 16, 0, 16, 0, 32, 0, stream);

        // conv2: 128 -> 64, post-agg, relu    bufA -> bufH
        launch_gemm<128, 64, 0, false, false, 8, 2>(bufA, nullptr, Wn[1], nullptr, nullptr,
                                                    zbuf, 32, 0, 0, 0, 16, 0, stream);
        launch_gather(zbuf, csr, rowoff, rdeg, aggb, 64, 16, 0, 16, 0, stream);
        launch_gemm<128, 64, 2, true, false, 8, 2>(bufA, aggb, Ws[1], nullptr, Bi[1],
                                                   bufH, 32, 0, 16, 0, 16, 0, stream);

        // conv3: 64 -> 32, post-agg, relu     bufH -> bufB cols 96..127 (off4 24)
        launch_gemm<64, 32, 0, false, false, 8, 1>(bufH, nullptr, Wn[2], nullptr, nullptr,
                                                   zbuf, 16, 0, 0, 0, 8, 0, stream);
        launch_gather(zbuf, csr, rowoff, rdeg, aggb, 32, 8, 0, 8, 0, stream);
        launch_gemm<64, 32, 2, true, false, 8, 1>(bufH, aggb, Ws[2], nullptr, Bi[2],
                                                  bufB, 16, 0, 8, 0, 32, 24, stream);

        // conv4: 32 -> 32, pre-agg, relu      bufB(+24 h3) -> bufB cols 64..95 (off4 16)
        // h3-agg goes to slots 8..15 of 64w agg (reused by conv5)
        launch_gather(bufB, csr, rowoff, rdeg, aggb, 32, 32, 24, 16, 8, stream);
        launch_gemm<32, 32, 1, true, false, 8, 1>(bufB, aggb, Ws[3], Wn[3], Bi[3],
                                                  bufB, 32, 24, 16, 8, 32, 16, stream);

        // conv5: 64 -> 64, pre-agg, relu      bufB(+16 h4) -> bufB cols 0..63
        // gather only c4 (cols 64..95) into slots 0..7; slots 8..15 = h3-agg from conv4
        launch_gather(bufB, csr, rowoff, rdeg, aggb, 32, 32, 16, 16, 0, stream);
        launch_gemm<64, 64, 1, true, false, 8, 2>(bufB, aggb, Ws[4], Wn[4], Bi[4],
                                                  bufB, 32, 16, 16, 0, 32, 0, stream);

        // conv6: 128 -> 64, post-agg, no relu  bufB(128w) -> bufH / d_out(transposed)
        launch_gemm<128, 64, 0, false, false, 8, 2>(bufB, nullptr, Wn[5], nullptr, nullptr,
                                                    zbuf, 32, 0, 0, 0, 16, 0, stream);
        launch_gather(zbuf, csr, rowoff, rdeg, aggb, 64, 16, 0, 16, 0, stream);
        if (last) {
            launch_gemm<128, 64, 2, false, true, 8, 2>(bufB, aggb, Ws[5], nullptr, Bi[5],
                                                       (float*)d_out, 32, 0, 16, 0, 16, 0, stream);
        } else {
            launch_gemm<128, 64, 2, false, false, 8, 2>(bufB, aggb, Ws[5], nullptr, Bi[5],
                                                        bufH, 32, 0, 16, 0, 16, 0, stream);
        }
    }
}

// Round 8
// 1108.018 us; speedup vs baseline: 9.9931x; 1.0071x over previous
//
#include <hip/hip_runtime.h>

#define NN 50000
#define NE 400000
#define BB 2
#define ROWS (NN * BB)   // 100000 feature rows, row r = node*2 + batch

#define SCAN_CHUNK 1024
#define SCAN_NB ((NN + SCAN_CHUNK - 1) / SCAN_CHUNK)   // 49 (<= 64)

__device__ inline void fma4(float4& a, float s, const float4& w) {
    a.x = fmaf(s, w.x, a.x); a.y = fmaf(s, w.y, a.y);
    a.z = fmaf(s, w.z, a.z); a.w = fmaf(s, w.w, a.w);
}
__device__ inline void add4(float4& a, const float4& v) {
    a.x += v.x; a.y += v.y; a.z += v.z; a.w += v.w;
}
__device__ inline unsigned bf2(float a, float b) {   // pack 2 floats -> 2 bf16 (RNE)
    unsigned ua = __float_as_uint(a); ua = (ua + 0x7FFFu + ((ua >> 16) & 1u)) >> 16;
    unsigned ub = __float_as_uint(b); ub = (ub + 0x7FFFu + ((ub >> 16) & 1u)) >> 16;
    return ua | (ub << 16);
}
__device__ inline void bfadd(float4& lo, float4& hi, uint4 v) {  // 8 bf16 += into fp32
    lo.x += __uint_as_float(v.x << 16); lo.y += __uint_as_float(v.x & 0xFFFF0000u);
    lo.z += __uint_as_float(v.y << 16); lo.w += __uint_as_float(v.y & 0xFFFF0000u);
    hi.x += __uint_as_float(v.z << 16); hi.y += __uint_as_float(v.z & 0xFFFF0000u);
    hi.z += __uint_as_float(v.w << 16); hi.w += __uint_as_float(v.w & 0xFFFF0000u);
}

// ---------------- CSR build ----------------

__global__ void k_hist(const int* __restrict__ dst, int* __restrict__ deg) {
    int e = blockIdx.x * 256 + threadIdx.x;
    if (e < NE) atomicAdd(&deg[dst[e]], 1);
}

__global__ __launch_bounds__(256) void k_scan1(const int* __restrict__ deg,
                                               int* __restrict__ bsum) {
    int b = blockIdx.x, t = threadIdx.x;
    int base = b * SCAN_CHUNK + t * 4;
    int s = 0;
#pragma unroll
    for (int i = 0; i < 4; i++) {
        int idx = base + i;
        if (idx < NN) s += deg[idx];
    }
    for (int d = 32; d; d >>= 1) s += __shfl_down(s, d);
    __shared__ int ws[4];
    if ((t & 63) == 0) ws[t >> 6] = s;
    __syncthreads();
    if (t == 0) bsum[b] = ws[0] + ws[1] + ws[2] + ws[3];
}

__global__ void k_scan2(const int* __restrict__ bsum, int* __restrict__ boff,
                        int* __restrict__ rowoff_last) {
    int lane = threadIdx.x;   // 64 threads
    int v = (lane < SCAN_NB) ? bsum[lane] : 0;
    int incl = v;
    for (int d = 1; d < 64; d <<= 1) {
        int o = __shfl_up(incl, d);
        if (lane >= d) incl += o;
    }
    if (lane < SCAN_NB) boff[lane] = incl - v;
    if (lane == 63) rowoff_last[0] = incl;
}

__global__ __launch_bounds__(256) void k_scan3(const int* __restrict__ deg,
                                               const int* __restrict__ boff,
                                               int* __restrict__ rowoff,
                                               int* __restrict__ cursor,
                                               float* __restrict__ rdeg) {
    int b = blockIdx.x, t = threadIdx.x;
    int lane = t & 63, wv = t >> 6;
    int base = b * SCAN_CHUNK + t * 4;
    int dv[4];
    int ts = 0;
#pragma unroll
    for (int i = 0; i < 4; i++) {
        int idx = base + i;
        dv[i] = (idx < NN) ? deg[idx] : 0;
        ts += dv[i];
    }
    int incl = ts;
    for (int d = 1; d < 64; d <<= 1) {
        int o = __shfl_up(incl, d);
        if (lane >= d) incl += o;
    }
    __shared__ int wsum[4];
    if (lane == 63) wsum[wv] = incl;
    __syncthreads();
    int wexc = 0;
    for (int w = 0; w < wv; w++) wexc += wsum[w];
    int run = boff[b] + wexc + (incl - ts);
#pragma unroll
    for (int i = 0; i < 4; i++) {
        int idx = base + i;
        if (idx < NN) {
            rowoff[idx] = run;
            cursor[idx] = run;
            rdeg[idx] = 1.0f / fmaxf((float)dv[i], 1.0f);
            run += dv[i];
        }
    }
}

__global__ void k_fill(const int* __restrict__ src, const int* __restrict__ dst,
                       int* __restrict__ cursor, int* __restrict__ csr) {
    int e = blockIdx.x * 256 + threadIdx.x;
    if (e >= NE) return;
    int pos = atomicAdd(&cursor[dst[e]], 1);
    csr[pos] = src[e];
}

// ---------------- aggregation ----------------

// fp32 mean-aggregate. Thread owns quad `tid` of BOTH batch rows of node n.
// x row (node s, batch b) at s*xns4 + b*xbs4 + xo4 (float4 units).
__global__ void k_gather(const float4* __restrict__ x, const int* __restrict__ csr,
                         const int* __restrict__ rowoff, const float* __restrict__ rdeg,
                         float4* __restrict__ out, int w4s,
                         int xns4, int xbs4, int xo4, int op4, int oo4) {
    int t = blockIdx.x * 256 + threadIdx.x;
    int n = t >> w4s, tid = t & ((1 << w4s) - 1);
    if (n >= NN) return;
    int beg = rowoff[n], end = rowoff[n + 1];
    int a0 = xo4 + tid;
    float4 c00 = {0.f,0.f,0.f,0.f}, c01 = {0.f,0.f,0.f,0.f};
    float4 c10 = {0.f,0.f,0.f,0.f}, c11 = {0.f,0.f,0.f,0.f};
    int j = beg;
    for (; j + 4 <= end; j += 4) {
        int s0 = csr[j], s1 = csr[j+1], s2 = csr[j+2], s3 = csr[j+3];
        int b0 = s0 * xns4 + a0, b1 = s1 * xns4 + a0;
        int b2 = s2 * xns4 + a0, b3 = s3 * xns4 + a0;
        float4 p0 = x[b0], q0 = x[b0 + xbs4];
        float4 p1 = x[b1], q1 = x[b1 + xbs4];
        float4 p2 = x[b2], q2 = x[b2 + xbs4];
        float4 p3 = x[b3], q3 = x[b3 + xbs4];
        add4(c00, p0); add4(c10, q0); add4(c01, p1); add4(c11, q1);
        add4(c00, p2); add4(c10, q2); add4(c01, p3); add4(c11, q3);
    }
    for (; j < end; j++) {
        int s = csr[j];
        int b = s * xns4 + a0;
        add4(c00, x[b]); add4(c10, x[b + xbs4]);
    }
    float rd = rdeg[n];
    float4 o0 = {(c00.x+c01.x)*rd, (c00.y+c01.y)*rd, (c00.z+c01.z)*rd, (c00.w+c01.w)*rd};
    float4 o1 = {(c10.x+c11.x)*rd, (c10.y+c11.y)*rd, (c10.z+c11.z)*rd, (c10.w+c11.w)*rd};
    out[(2*n)     * op4 + oo4 + tid] = o0;
    out[(2*n + 1) * op4 + oo4 + tid] = o1;
}

// bf16 mean-aggregate (z path). z packed: row r=2n+b is rp8 uint4 (8 bf16 each).
// Thread owns uint4 `tid` (8 cols) of both batch rows; writes fp32 aggb.
__global__ void k_gather_bf(const uint4* __restrict__ x, const int* __restrict__ csr,
                            const int* __restrict__ rowoff, const float* __restrict__ rdeg,
                            float4* __restrict__ out, int w8s, int op4, int oo4) {
    int t = blockIdx.x * 256 + threadIdx.x;
    int n = t >> w8s, tid = t & ((1 << w8s) - 1);
    if (n >= NN) return;
    int rp8 = 1 << w8s, nrp = 2 << w8s;
    int beg = rowoff[n], end = rowoff[n + 1];
    float4 a0l = {0.f,0.f,0.f,0.f}, a0h = {0.f,0.f,0.f,0.f};
    float4 a1l = {0.f,0.f,0.f,0.f}, a1h = {0.f,0.f,0.f,0.f};
    int j = beg;
    for (; j + 2 <= end; j += 2) {
        int s0 = csr[j], s1 = csr[j+1];
        int b0 = s0 * nrp + tid, b1 = s1 * nrp + tid;
        uint4 p0 = x[b0], q0 = x[b0 + rp8];
        uint4 p1 = x[b1], q1 = x[b1 + rp8];
        bfadd(a0l, a0h, p0); bfadd(a1l, a1h, q0);
        bfadd(a0l, a0h, p1); bfadd(a1l, a1h, q1);
    }
    if (j < end) {
        int s = csr[j];
        int b = s * nrp + tid;
        bfadd(a0l, a0h, x[b]); bfadd(a1l, a1h, x[b + rp8]);
    }
    float rd = rdeg[n];
    float4 o0l = {a0l.x*rd, a0l.y*rd, a0l.z*rd, a0l.w*rd};
    float4 o0h = {a0h.x*rd, a0h.y*rd, a0h.z*rd, a0h.w*rd};
    float4 o1l = {a1l.x*rd, a1l.y*rd, a1l.z*rd, a1l.w*rd};
    float4 o1h = {a1h.x*rd, a1h.y*rd, a1h.z*rd, a1h.w*rd};
    int r0 = (2*n) * op4 + oo4 + 2*tid;
    int r1 = (2*n + 1) * op4 + oo4 + 2*tid;
    out[r0] = o0l; out[r0 + 1] = o0h;
    out[r1] = o1l; out[r1 + 1] = o1h;
}

// ---------------- tiled GEMM / SAGE transform ----------------
// MODE 0: out = x @ w0                        (OBF: write bf16, pitch in uint2 = ostride4)
// MODE 1: out = act(x @ w0 + agg @ w1 + b)
// MODE 2: out = act(x @ w0 + agg + b)
// Thread: RPT rows x NCQ col-quads. CS col-split blocks (blockIdx.y).
template<int FIN, int FOUT, int MODE, bool RELU, bool TRANS, int RPT, int NCQ, int CS, bool OBF>
__global__ __launch_bounds__(256) void k_gemm(
    const float* __restrict__ x, const float* __restrict__ agg,
    const float* __restrict__ w0, const float* __restrict__ w1,
    const float* __restrict__ bias, float* __restrict__ out,
    int xns4, int xbs4, int xo4, int apitch4, int aoff4, int ostride4, int ooff4)
{
    constexpr int NQ = FOUT / 4;        // total col quads
    constexpr int NQB = NQ / CS;        // col quads per block
    constexpr int TX = NQB / NCQ;       // threads across cols
    constexpr int TY = 256 / TX;
    constexpr int TM = TY * RPT;        // rows per block
    constexpr int W4B = FIN * NQB;      // staged float4s per matrix
    constexpr int NW = (MODE == 1) ? 2 : 1;

    __shared__ float4 wlds[NW * W4B];   // <= 32 KB

    int t = threadIdx.x;
    int cq0 = blockIdx.y * NQB;
    const float4* w0v = (const float4*)w0;
    for (int i = t; i < W4B; i += 256)
        wlds[i] = w0v[(i / NQB) * NQ + cq0 + (i % NQB)];
    if (MODE == 1) {
        const float4* w1v = (const float4*)w1;
        for (int i = t; i < W4B; i += 256)
            wlds[W4B + i] = w1v[(i / NQB) * NQ + cq0 + (i % NQB)];
    }
    __syncthreads();

    int tx = t % TX, ty = t / TX;
    int rbase = blockIdx.x * TM + ty * RPT;

    int xb[RPT], ab[RPT];
#pragma unroll
    for (int i = 0; i < RPT; i++) {
        int r = rbase + i;
        r = r < ROWS ? r : ROWS - 1;
        xb[i] = (r >> 1) * xns4 + (r & 1) * xbs4 + xo4;
        ab[i] = r * apitch4 + aoff4;
    }

    float4 acc[RPT][NCQ];
#pragma unroll
    for (int i = 0; i < RPT; i++)
#pragma unroll
        for (int j = 0; j < NCQ; j++) acc[i][j] = make_float4(0.f, 0.f, 0.f, 0.f);

    const float4* xv4 = (const float4*)x;
    const float4* av4 = (const float4*)agg;

    for (int k4 = 0; k4 < FIN / 4; k4++) {
        float4 wq[4][NCQ], nq[4][NCQ];
#pragma unroll
        for (int u = 0; u < 4; u++)
#pragma unroll
            for (int j = 0; j < NCQ; j++) {
                wq[u][j] = wlds[(k4 * 4 + u) * NQB + tx + j * TX];
                if (MODE == 1) nq[u][j] = wlds[W4B + (k4 * 4 + u) * NQB + tx + j * TX];
            }
#pragma unroll
        for (int i = 0; i < RPT; i++) {
            float4 xv = xv4[xb[i] + k4];
#pragma unroll
            for (int j = 0; j < NCQ; j++) {
                fma4(acc[i][j], xv.x, wq[0][j]); fma4(acc[i][j], xv.y, wq[1][j]);
                fma4(acc[i][j], xv.z, wq[2][j]); fma4(acc[i][j], xv.w, wq[3][j]);
            }
            if (MODE == 1) {
                float4 av = av4[ab[i] + k4];
#pragma unroll
                for (int j = 0; j < NCQ; j++) {
                    fma4(acc[i][j], av.x, nq[0][j]); fma4(acc[i][j], av.y, nq[1][j]);
                    fma4(acc[i][j], av.z, nq[2][j]); fma4(acc[i][j], av.w, nq[3][j]);
                }
            }
        }
    }

    float4 b4[NCQ];
#pragma unroll
    for (int j = 0; j < NCQ; j++) {
        b4[j] = make_float4(0.f, 0.f, 0.f, 0.f);
        if (MODE != 0) b4[j] = *(const float4*)&bias[(cq0 + tx + j * TX) * 4];
    }

#pragma unroll
    for (int i = 0; i < RPT; i++) {
        int r = rbase + i;
        if (r >= ROWS) continue;
#pragma unroll
        for (int j = 0; j < NCQ; j++) {
            int q = cq0 + tx + j * TX;
            float4 v = acc[i][j];
            if (MODE == 2) {
                float4 ag = av4[ab[i] + q];
                add4(v, ag);
            }
            if (MODE != 0) add4(v, b4[j]);
            if (RELU) {
                v.x = fmaxf(v.x, 0.f); v.y = fmaxf(v.y, 0.f);
                v.z = fmaxf(v.z, 0.f); v.w = fmaxf(v.w, 0.f);
            }
            if (OBF) {
                uint2 w; w.x = bf2(v.x, v.y); w.y = bf2(v.z, v.w);
                ((uint2*)out)[r * ostride4 + ooff4 + q] = w;
            } else {
                int oidx;
                if (TRANS) {                   // FOUT==64 here
                    int n = r >> 1, b = r & 1;
                    oidx = b * (NN * 16) + n * 16 + q;
                } else {
                    oidx = r * ostride4 + ooff4 + q;
                }
                ((float4*)out)[oidx] = v;
            }
        }
    }
}

// ---------------- host ----------------

template<int FIN, int FOUT, int MODE, bool RELU, bool TRANS,
         int RPT = 8, int NCQ = 1, int CS = 1, bool OBF = false>
static void launch_gemm(const float* x, const float* agg, const float* w0, const float* w1,
                        const float* bias, float* out, int xns4, int xbs4, int xo4,
                        int apitch4, int aoff4, int ostride4, int ooff4,
                        hipStream_t stream) {
    constexpr int TM = (256 / (FOUT / 4 / CS / NCQ)) * RPT;
    int nb = (ROWS + TM - 1) / TM;
    k_gemm<FIN, FOUT, MODE, RELU, TRANS, RPT, NCQ, CS, OBF>
        <<<dim3(nb, CS), 256, 0, stream>>>(
        x, agg, w0, w1, bias, out, xns4, xbs4, xo4, apitch4, aoff4, ostride4, ooff4);
}

static void launch_gather(const float* x, const int* csr, const int* rowoff,
                          const float* rdeg, float* aggb, int width,
                          int xns4, int xbs4, int xo4, int op4, int oo4,
                          hipStream_t stream) {
    int w4s = 0;
    while ((1 << w4s) < width / 4) w4s++;
    int gt = NN << w4s;
    k_gather<<<(gt + 255) / 256, 256, 0, stream>>>(
        (const float4*)x, csr, rowoff, rdeg, (float4*)aggb, w4s,
        xns4, xbs4, xo4, op4, oo4);
}

static void launch_gather_bf(const float* z, const int* csr, const int* rowoff,
                             const float* rdeg, float* aggb, int width,
                             int op4, int oo4, hipStream_t stream) {
    int w8s = 0;
    while ((1 << w8s) < width / 8) w8s++;
    int gt = NN << w8s;
    k_gather_bf<<<(gt + 255) / 256, 256, 0, stream>>>(
        (const uint4*)z, csr, rowoff, rdeg, (float4*)aggb, w8s, op4, oo4);
}

extern "C" void kernel_launch(void* const* d_in, const int* in_sizes, int n_in,
                              void* d_out, int out_size, void* d_ws, size_t ws_size,
                              hipStream_t stream) {
    const float* in_feat = (const float*)d_in[0];
    const int* src = (const int*)d_in[1];
    const int* dst = (const int*)d_in[2];
    const float* Ws[6], *Wn[6], *Bi[6];
    for (int i = 0; i < 6; i++) {
        Ws[i] = (const float*)d_in[3 + 3 * i];
        Wn[i] = (const float*)d_in[4 + 3 * i];
        Bi[i] = (const float*)d_in[5 + 3 * i];
    }

    char* ws = (char*)d_ws;
    size_t off = 0;
    auto alloc = [&](size_t bytes) {
        void* p = ws + off;
        off = (off + bytes + 255) & ~(size_t)255;
        return p;
    };
    float* rdeg   = (float*)alloc((size_t)NN * 4);
    int*   deg    = (int*)  alloc((size_t)NN * 4);
    int*   rowoff = (int*)  alloc((size_t)(NN + 1) * 4);
    int*   cursor = (int*)  alloc((size_t)NN * 4);
    int*   csr    = (int*)  alloc((size_t)NE * 4);
    int*   bsum   = (int*)  alloc((size_t)SCAN_NB * 4);
    int*   boff   = (int*)  alloc((size_t)SCAN_NB * 4);
    float* bufH   = (float*)alloc((size_t)ROWS * 64 * 4);    // h2 mid-step; h between steps
    float* bufA   = (float*)alloc((size_t)ROWS * 128 * 4);   // h1 (128w)
    float* bufB   = (float*)alloc((size_t)ROWS * 128 * 4);   // h5 concat home [c5|c4|h3]
    float* aggb   = (float*)alloc((size_t)ROWS * 64 * 4);    // packed fp32 agg, 64w layout
    float* zbuf   = (float*)d_out;   // bf16 z scratch; dead before final d_out write

    // CSR build (ws re-poisoned every call)
    hipMemsetAsync(deg, 0, (size_t)NN * 4, stream);
    k_hist<<<(NE + 255) / 256, 256, 0, stream>>>(dst, deg);
    k_scan1<<<SCAN_NB, 256, 0, stream>>>(deg, bsum);
    k_scan2<<<1, 64, 0, stream>>>(bsum, boff, rowoff + NN);
    k_scan3<<<SCAN_NB, 256, 0, stream>>>(deg, boff, rowoff, cursor, rdeg);
    k_fill<<<(NE + 255) / 256, 256, 0, stream>>>(src, dst, cursor, csr);

    const int BSTR = NN * 16;   // in_feat batch stride (float4)

    for (int s = 0; s < 2; s++) {
        int last = (s == 1);
        // step-1 input: in_feat [B,N,64] (node stride 16, batch stride NN*16)
        // step-2 input: bufH packed 64w (node stride 32, batch stride 16)
        const float* hx = s ? bufH : in_feat;
        int hns = s ? 32 : 16, hbs = s ? 16 : BSTR;

        // conv1: 64 -> 128, pre-agg, relu     hx -> bufA (packed 128w); col-split 2
        launch_gather(hx, csr, rowoff, rdeg, aggb, 64, hns, hbs, 0, 16, 0, stream);
        launch_gemm<64, 128, 1, true, false, 8, 2, 2>(hx, aggb, Ws[0], Wn[0], Bi[0],
                                                      bufA, hns, hbs, 0, 16, 0, 32, 0, stream);

        // conv2: 128 -> 64, post-agg, relu    bufA -> bufH (z in bf16)
        launch_gemm<128, 64, 0, false, false, 8, 2, 1, true>(
            bufA, nullptr, Wn[1], nullptr, nullptr, zbuf, 64, 32, 0, 0, 0, 16, 0, stream);
        launch_gather_bf(zbuf, csr, rowoff, rdeg, aggb, 64, 16, 0, stream);
        launch_gemm<128, 64, 2, true, false, 8, 2>(bufA, aggb, Ws[1], nullptr, Bi[1],
                                                   bufH, 64, 32, 0, 16, 0, 16, 0, stream);

        // conv3: 64 -> 32, post-agg, relu     bufH -> bufB cols 96..127 (off4 24)
        launch_gemm<64, 32, 0, false, false, 8, 1, 1, true>(
            bufH, nullptr, Wn[2], nullptr, nullptr, zbuf, 32, 16, 0, 0, 0, 8, 0, stream);
        launch_gather_bf(zbuf, csr, rowoff, rdeg, aggb, 32, 8, 0, stream);
        launch_gemm<64, 32, 2, true, false, 8, 1>(bufH, aggb, Ws[2], nullptr, Bi[2],
                                                  bufB, 32, 16, 0, 8, 0, 32, 24, stream);

        // conv4: 32 -> 32, pre-agg, relu      bufB(+24 h3) -> bufB cols 64..95 (off4 16)
        // h3-agg into slots 8..15 of 64w aggb (reused by conv5)
        launch_gather(bufB, csr, rowoff, rdeg, aggb, 32, 64, 32, 24, 16, 8, stream);
        launch_gemm<32, 32, 1, true, false, 8, 1>(bufB, aggb, Ws[3], Wn[3], Bi[3],
                                                  bufB, 64, 32, 24, 16, 8, 32, 16, stream);

        // conv5: 64 -> 64, pre-agg, relu      bufB(+16 h4) -> bufB cols 0..63
        // gather only c4 into slots 0..7; slots 8..15 = h3-agg from conv4
        launch_gather(bufB, csr, rowoff, rdeg, aggb, 32, 64, 32, 16, 16, 0, stream);
        launch_gemm<64, 64, 1, true, false, 8, 2>(bufB, aggb, Ws[4], Wn[4], Bi[4],
                                                  bufB, 64, 32, 16, 16, 0, 32, 0, stream);

        // conv6: 128 -> 64, post-agg, no relu  bufB(128w) -> bufH / d_out(transposed)
        launch_gemm<128, 64, 0, false, false, 8, 2, 1, true>(
            bufB, nullptr, Wn[5], nullptr, nullptr, zbuf, 64, 32, 0, 0, 0, 16, 0, stream);
        launch_gather_bf(zbuf, csr, rowoff, rdeg, aggb, 64, 16, 0, stream);
        if (last) {
            launch_gemm<128, 64, 2, false, true, 8, 2>(bufB, aggb, Ws[5], nullptr, Bi[5],
                                                       (float*)d_out, 64, 32, 0, 16, 0, 16, 0, stream);
        } else {
            launch_gemm<128, 64, 2, false, false, 8, 2>(bufB, aggb, Ws[5], nullptr, Bi[5],
                                                        bufH, 64, 32, 0, 16, 0, 16, 0, stream);
        }
    }
}

// Round 9
// 977.142 us; speedup vs baseline: 11.3316x; 1.1339x over previous
//
#include <hip/hip_runtime.h>

#define NN 50000
#define NE 400000
#define BB 2
#define ROWS (NN * BB)   // 100000 feature rows, row r = node*2 + batch

#define SCAN_CHUNK 1024
#define SCAN_NB ((NN + SCAN_CHUNK - 1) / SCAN_CHUNK)   // 49 (<= 64)

__device__ inline void fma4(float4& a, float s, const float4& w) {
    a.x = fmaf(s, w.x, a.x); a.y = fmaf(s, w.y, a.y);
    a.z = fmaf(s, w.z, a.z); a.w = fmaf(s, w.w, a.w);
}
__device__ inline void add4(float4& a, const float4& v) {
    a.x += v.x; a.y += v.y; a.z += v.z; a.w += v.w;
}
__device__ inline unsigned bf2(float a, float b) {   // pack 2 floats -> 2 bf16 (RNE)
    unsigned ua = __float_as_uint(a); ua = (ua + 0x7FFFu + ((ua >> 16) & 1u)) >> 16;
    unsigned ub = __float_as_uint(b); ub = (ub + 0x7FFFu + ((ub >> 16) & 1u)) >> 16;
    return ua | (ub << 16);
}
__device__ inline void bfadd(float4& lo, float4& hi, uint4 v) {  // 8 bf16 += into fp32
    lo.x += __uint_as_float(v.x << 16); lo.y += __uint_as_float(v.x & 0xFFFF0000u);
    lo.z += __uint_as_float(v.y << 16); lo.w += __uint_as_float(v.y & 0xFFFF0000u);
    hi.x += __uint_as_float(v.z << 16); hi.y += __uint_as_float(v.z & 0xFFFF0000u);
    hi.z += __uint_as_float(v.w << 16); hi.w += __uint_as_float(v.w & 0xFFFF0000u);
}

// ---------------- CSR build ----------------

__global__ void k_hist(const int* __restrict__ dst, int* __restrict__ deg) {
    int e = blockIdx.x * 256 + threadIdx.x;
    if (e < NE) atomicAdd(&deg[dst[e]], 1);
}

__global__ __launch_bounds__(256) void k_scan1(const int* __restrict__ deg,
                                               int* __restrict__ bsum) {
    int b = blockIdx.x, t = threadIdx.x;
    int base = b * SCAN_CHUNK + t * 4;
    int s = 0;
#pragma unroll
    for (int i = 0; i < 4; i++) {
        int idx = base + i;
        if (idx < NN) s += deg[idx];
    }
    for (int d = 32; d; d >>= 1) s += __shfl_down(s, d);
    __shared__ int ws[4];
    if ((t & 63) == 0) ws[t >> 6] = s;
    __syncthreads();
    if (t == 0) bsum[b] = ws[0] + ws[1] + ws[2] + ws[3];
}

__global__ void k_scan2(const int* __restrict__ bsum, int* __restrict__ boff,
                        int* __restrict__ rowoff_last) {
    int lane = threadIdx.x;   // 64 threads
    int v = (lane < SCAN_NB) ? bsum[lane] : 0;
    int incl = v;
    for (int d = 1; d < 64; d <<= 1) {
        int o = __shfl_up(incl, d);
        if (lane >= d) incl += o;
    }
    if (lane < SCAN_NB) boff[lane] = incl - v;
    if (lane == 63) rowoff_last[0] = incl;
}

__global__ __launch_bounds__(256) void k_scan3(const int* __restrict__ deg,
                                               const int* __restrict__ boff,
                                               int* __restrict__ rowoff,
                                               int* __restrict__ cursor,
                                               float* __restrict__ rdeg) {
    int b = blockIdx.x, t = threadIdx.x;
    int lane = t & 63, wv = t >> 6;
    int base = b * SCAN_CHUNK + t * 4;
    int dv[4];
    int ts = 0;
#pragma unroll
    for (int i = 0; i < 4; i++) {
        int idx = base + i;
        dv[i] = (idx < NN) ? deg[idx] : 0;
        ts += dv[i];
    }
    int incl = ts;
    for (int d = 1; d < 64; d <<= 1) {
        int o = __shfl_up(incl, d);
        if (lane >= d) incl += o;
    }
    __shared__ int wsum[4];
    if (lane == 63) wsum[wv] = incl;
    __syncthreads();
    int wexc = 0;
    for (int w = 0; w < wv; w++) wexc += wsum[w];
    int run = boff[b] + wexc + (incl - ts);
#pragma unroll
    for (int i = 0; i < 4; i++) {
        int idx = base + i;
        if (idx < NN) {
            rowoff[idx] = run;
            cursor[idx] = run;
            rdeg[idx] = 1.0f / fmaxf((float)dv[i], 1.0f);
            run += dv[i];
        }
    }
}

__global__ void k_fill(const int* __restrict__ src, const int* __restrict__ dst,
                       int* __restrict__ cursor, int* __restrict__ csr) {
    int e = blockIdx.x * 256 + threadIdx.x;
    if (e >= NE) return;
    int pos = atomicAdd(&cursor[dst[e]], 1);
    csr[pos] = src[e];
}

// ---------------- bf16 shadow pack: in_feat [B,N,64] -> hbf [ROWS][8 uint4] ----------------

__global__ void k_pack(const float4* __restrict__ in, uint4* __restrict__ out) {
    int t = blockIdx.x * 256 + threadIdx.x;
    if (t >= ROWS * 8) return;
    int r = t >> 3, k = t & 7;
    int n = r >> 1, b = r & 1;
    float4 a = in[(b * NN + n) * 16 + k * 2];
    float4 c = in[(b * NN + n) * 16 + k * 2 + 1];
    uint4 o;
    o.x = bf2(a.x, a.y); o.y = bf2(a.z, a.w);
    o.z = bf2(c.x, c.y); o.w = bf2(c.z, c.w);
    out[t] = o;
}

// ---------------- bf16 mean-aggregate ----------------
// x rows (node s, batch b) at (2s+b)*xp8 + xo8 (uint4 units, 8 bf16 each).
// Thread owns uint4 `tid` (8 cols) of both batch rows; writes fp32 aggb.
__global__ void k_gather_bf(const uint4* __restrict__ x, const int* __restrict__ csr,
                            const int* __restrict__ rowoff, const float* __restrict__ rdeg,
                            float4* __restrict__ out, int w8s, int xp8, int xo8,
                            int op4, int oo4) {
    int t = blockIdx.x * 256 + threadIdx.x;
    int n = t >> w8s, tid = t & ((1 << w8s) - 1);
    if (n >= NN) return;
    int beg = rowoff[n], end = rowoff[n + 1];
    int a0 = xo8 + tid;
    int xp2 = 2 * xp8;
    float4 a0l = {0.f,0.f,0.f,0.f}, a0h = {0.f,0.f,0.f,0.f};
    float4 a1l = {0.f,0.f,0.f,0.f}, a1h = {0.f,0.f,0.f,0.f};
    int j = beg;
    for (; j + 2 <= end; j += 2) {
        int s0 = csr[j], s1 = csr[j+1];
        int b0 = s0 * xp2 + a0, b1 = s1 * xp2 + a0;
        uint4 p0 = x[b0], q0 = x[b0 + xp8];
        uint4 p1 = x[b1], q1 = x[b1 + xp8];
        bfadd(a0l, a0h, p0); bfadd(a1l, a1h, q0);
        bfadd(a0l, a0h, p1); bfadd(a1l, a1h, q1);
    }
    if (j < end) {
        int s = csr[j];
        int b = s * xp2 + a0;
        bfadd(a0l, a0h, x[b]); bfadd(a1l, a1h, x[b + xp8]);
    }
    float rd = rdeg[n];
    float4 o0l = {a0l.x*rd, a0l.y*rd, a0l.z*rd, a0l.w*rd};
    float4 o0h = {a0h.x*rd, a0h.y*rd, a0h.z*rd, a0h.w*rd};
    float4 o1l = {a1l.x*rd, a1l.y*rd, a1l.z*rd, a1l.w*rd};
    float4 o1h = {a1h.x*rd, a1h.y*rd, a1h.z*rd, a1h.w*rd};
    int r0 = (2*n) * op4 + oo4 + 2*tid;
    int r1 = (2*n + 1) * op4 + oo4 + 2*tid;
    out[r0] = o0l; out[r0 + 1] = o0h;
    out[r1] = o1l; out[r1 + 1] = o1h;
}

// ---------------- tiled GEMM / SAGE transform ----------------
// MODE 0: out = x @ w0                        (OBF: write bf16, ostride4/ooff4 in uint2)
// MODE 1: out = act(x @ w0 + agg @ w1 + b)
// MODE 2: out = act(x @ w0 + agg + b)
// DUAL: additionally write bf16 copy of result to bfo (uint2 pitch bfp2, off bfo2).
template<int FIN, int FOUT, int MODE, bool RELU, bool TRANS, int RPT, int NCQ, bool OBF, bool DUAL>
__global__ __launch_bounds__(256) void k_gemm(
    const float* __restrict__ x, const float* __restrict__ agg,
    const float* __restrict__ w0, const float* __restrict__ w1,
    const float* __restrict__ bias, float* __restrict__ out,
    int xns4, int xbs4, int xo4, int apitch4, int aoff4, int ostride4, int ooff4,
    uint2* __restrict__ bfo, int bfp2, int bfo2)
{
    constexpr int NQ = FOUT / 4;        // col quads
    constexpr int TX = NQ / NCQ;        // threads across cols
    constexpr int TY = 256 / TX;
    constexpr int TM = TY * RPT;        // rows per block
    constexpr int W4 = FIN * NQ;        // staged float4s per matrix
    constexpr int NW = (MODE == 1) ? 2 : 1;

    __shared__ float4 wlds[NW * W4];    // max 64 KB (conv1)

    int t = threadIdx.x;
    const float4* w0v = (const float4*)w0;
    for (int i = t; i < W4; i += 256) wlds[i] = w0v[i];
    if (MODE == 1) {
        const float4* w1v = (const float4*)w1;
        for (int i = t; i < W4; i += 256) wlds[W4 + i] = w1v[i];
    }
    __syncthreads();

    int tx = t % TX, ty = t / TX;
    int rbase = blockIdx.x * TM + ty * RPT;

    int xb[RPT], ab[RPT];
#pragma unroll
    for (int i = 0; i < RPT; i++) {
        int r = rbase + i;
        r = r < ROWS ? r : ROWS - 1;
        xb[i] = (r >> 1) * xns4 + (r & 1) * xbs4 + xo4;
        ab[i] = r * apitch4 + aoff4;
    }

    float4 acc[RPT][NCQ];
#pragma unroll
    for (int i = 0; i < RPT; i++)
#pragma unroll
        for (int j = 0; j < NCQ; j++) acc[i][j] = make_float4(0.f, 0.f, 0.f, 0.f);

    const float4* xv4 = (const float4*)x;
    const float4* av4 = (const float4*)agg;

    for (int k4 = 0; k4 < FIN / 4; k4++) {
        float4 wq[4][NCQ], nq[4][NCQ];
#pragma unroll
        for (int u = 0; u < 4; u++)
#pragma unroll
            for (int j = 0; j < NCQ; j++) {
                wq[u][j] = wlds[(k4 * 4 + u) * NQ + tx + j * TX];
                if (MODE == 1) nq[u][j] = wlds[W4 + (k4 * 4 + u) * NQ + tx + j * TX];
            }
#pragma unroll
        for (int i = 0; i < RPT; i++) {
            float4 xv = xv4[xb[i] + k4];
#pragma unroll
            for (int j = 0; j < NCQ; j++) {
                fma4(acc[i][j], xv.x, wq[0][j]); fma4(acc[i][j], xv.y, wq[1][j]);
                fma4(acc[i][j], xv.z, wq[2][j]); fma4(acc[i][j], xv.w, wq[3][j]);
            }
            if (MODE == 1) {
                float4 av = av4[ab[i] + k4];
#pragma unroll
                for (int j = 0; j < NCQ; j++) {
                    fma4(acc[i][j], av.x, nq[0][j]); fma4(acc[i][j], av.y, nq[1][j]);
                    fma4(acc[i][j], av.z, nq[2][j]); fma4(acc[i][j], av.w, nq[3][j]);
                }
            }
        }
    }

    float4 b4[NCQ];
#pragma unroll
    for (int j = 0; j < NCQ; j++) {
        b4[j] = make_float4(0.f, 0.f, 0.f, 0.f);
        if (MODE != 0) b4[j] = *(const float4*)&bias[(tx + j * TX) * 4];
    }

#pragma unroll
    for (int i = 0; i < RPT; i++) {
        int r = rbase + i;
        if (r >= ROWS) continue;
#pragma unroll
        for (int j = 0; j < NCQ; j++) {
            int q = tx + j * TX;
            float4 v = acc[i][j];
            if (MODE == 2) {
                float4 ag = av4[ab[i] + q];
                add4(v, ag);
            }
            if (MODE != 0) add4(v, b4[j]);
            if (RELU) {
                v.x = fmaxf(v.x, 0.f); v.y = fmaxf(v.y, 0.f);
                v.z = fmaxf(v.z, 0.f); v.w = fmaxf(v.w, 0.f);
            }
            if (OBF) {
                uint2 w; w.x = bf2(v.x, v.y); w.y = bf2(v.z, v.w);
                ((uint2*)out)[r * ostride4 + ooff4 + q] = w;
            } else {
                int oidx;
                if (TRANS) {                   // FOUT==64 here
                    int n = r >> 1, b = r & 1;
                    oidx = b * (NN * 16) + n * 16 + q;
                } else {
                    oidx = r * ostride4 + ooff4 + q;
                }
                ((float4*)out)[oidx] = v;
            }
            if (DUAL) {
                uint2 w; w.x = bf2(v.x, v.y); w.y = bf2(v.z, v.w);
                bfo[r * bfp2 + bfo2 + q] = w;
            }
        }
    }
}

// ---------------- host ----------------

template<int FIN, int FOUT, int MODE, bool RELU, bool TRANS,
         int RPT = 8, int NCQ = 1, bool OBF = false, bool DUAL = false>
static void launch_gemm(const float* x, const float* agg, const float* w0, const float* w1,
                        const float* bias, float* out, int xns4, int xbs4, int xo4,
                        int apitch4, int aoff4, int ostride4, int ooff4,
                        hipStream_t stream,
                        uint2* bfo = nullptr, int bfp2 = 0, int bfo2 = 0) {
    constexpr int TM = (256 / (FOUT / 4 / NCQ)) * RPT;
    int nb = (ROWS + TM - 1) / TM;
    k_gemm<FIN, FOUT, MODE, RELU, TRANS, RPT, NCQ, OBF, DUAL><<<nb, 256, 0, stream>>>(
        x, agg, w0, w1, bias, out, xns4, xbs4, xo4, apitch4, aoff4, ostride4, ooff4,
        bfo, bfp2, bfo2);
}

// width in floats; bf16 source rows at (2s+b)*xp8 + xo8 (uint4)
static void launch_gather_bf(const void* xbf, const int* csr, const int* rowoff,
                             const float* rdeg, float* aggb, int width,
                             int xp8, int xo8, int op4, int oo4, hipStream_t stream) {
    int w8s = 0;
    while ((1 << w8s) < width / 8) w8s++;
    int gt = NN << w8s;
    k_gather_bf<<<(gt + 255) / 256, 256, 0, stream>>>(
        (const uint4*)xbf, csr, rowoff, rdeg, (float4*)aggb, w8s, xp8, xo8, op4, oo4);
}

extern "C" void kernel_launch(void* const* d_in, const int* in_sizes, int n_in,
                              void* d_out, int out_size, void* d_ws, size_t ws_size,
                              hipStream_t stream) {
    const float* in_feat = (const float*)d_in[0];
    const int* src = (const int*)d_in[1];
    const int* dst = (const int*)d_in[2];
    const float* Ws[6], *Wn[6], *Bi[6];
    for (int i = 0; i < 6; i++) {
        Ws[i] = (const float*)d_in[3 + 3 * i];
        Wn[i] = (const float*)d_in[4 + 3 * i];
        Bi[i] = (const float*)d_in[5 + 3 * i];
    }

    char* ws = (char*)d_ws;
    size_t off = 0;
    auto alloc = [&](size_t bytes) {
        void* p = ws + off;
        off = (off + bytes + 255) & ~(size_t)255;
        return p;
    };
    float* rdeg   = (float*)alloc((size_t)NN * 4);
    int*   deg    = (int*)  alloc((size_t)NN * 4);
    int*   rowoff = (int*)  alloc((size_t)(NN + 1) * 4);
    int*   cursor = (int*)  alloc((size_t)NN * 4);
    int*   csr    = (int*)  alloc((size_t)NE * 4);
    int*   bsum   = (int*)  alloc((size_t)SCAN_NB * 4);
    int*   boff   = (int*)  alloc((size_t)SCAN_NB * 4);
    float* bufH   = (float*)alloc((size_t)ROWS * 64 * 4);    // h2 mid-step; h between steps
    float* bufA   = (float*)alloc((size_t)ROWS * 128 * 4);   // h1 (128w)
    float* bufB   = (float*)alloc((size_t)ROWS * 128 * 4);   // h5 concat home [c5|c4|h3]
    float* aggb   = (float*)alloc((size_t)ROWS * 64 * 4);    // packed fp32 agg, 64w
    float* zbuf   = (float*)d_out;   // bf16 z scratch; dead before final d_out write

    // bf16 gather-source shadows ALIAS bufA's dead window (bufA=h1 is live only
    // conv1-gemm-write .. conv2-final-gemm-read; hbf/b3bf live conv3 .. next conv1-gather):
    uint2* hbf  = (uint2*)bufA;                       // h shadow  [ROWS][16 uint2] 12.8 MB
    uint2* b3bf = (uint2*)(bufA + (size_t)ROWS * 32); // [c4|h3]   [ROWS][16 uint2] 12.8 MB

    // CSR build (ws re-poisoned every call)
    hipMemsetAsync(deg, 0, (size_t)NN * 4, stream);
    k_hist<<<(NE + 255) / 256, 256, 0, stream>>>(dst, deg);
    k_scan1<<<SCAN_NB, 256, 0, stream>>>(deg, bsum);
    k_scan2<<<1, 64, 0, stream>>>(bsum, boff, rowoff + NN);
    k_scan3<<<SCAN_NB, 256, 0, stream>>>(deg, boff, rowoff, cursor, rdeg);
    k_fill<<<(NE + 255) / 256, 256, 0, stream>>>(src, dst, cursor, csr);

    // bf16 pack of in_feat for step-1 conv1 gather
    k_pack<<<(ROWS * 8 + 255) / 256, 256, 0, stream>>>((const float4*)in_feat, (uint4*)hbf);

    const int BSTR = NN * 16;   // in_feat batch stride (float4)

    for (int s = 0; s < 2; s++) {
        int last = (s == 1);
        // conv1 gemm x: step-1 = in_feat (node stride 16, batch stride NN*16),
        //               step-2 = bufH packed 64w (node stride 32, batch stride 16)
        const float* hx = s ? bufH : in_feat;
        int hns = s ? 32 : 16, hbs = s ? 16 : BSTR;

        // conv1: 64 -> 128, pre-agg, relu     hx -> bufA (packed 128w)
        launch_gather_bf(hbf, csr, rowoff, rdeg, aggb, 64, 8, 0, 16, 0, stream);
        launch_gemm<64, 128, 1, true, false, 8, 2>(hx, aggb, Ws[0], Wn[0], Bi[0],
                                                   bufA, hns, hbs, 0, 16, 0, 32, 0, stream);

        // conv2: 128 -> 64, post-agg, relu    bufA -> bufH (z bf16 via zbuf)
        launch_gemm<128, 64, 0, false, false, 8, 2, true>(
            bufA, nullptr, Wn[1], nullptr, nullptr, zbuf, 64, 32, 0, 0, 0, 16, 0, stream);
        launch_gather_bf(zbuf, csr, rowoff, rdeg, aggb, 64, 8, 0, 16, 0, stream);
        launch_gemm<128, 64, 2, true, false, 8, 2>(bufA, aggb, Ws[1], nullptr, Bi[1],
                                                   bufH, 64, 32, 0, 16, 0, 16, 0, stream);

        // conv3: 64 -> 32, post-agg, relu     bufH -> bufB cols 96..127; dual bf16 h3
        launch_gemm<64, 32, 0, false, false, 8, 1, true>(
            bufH, nullptr, Wn[2], nullptr, nullptr, zbuf, 32, 16, 0, 0, 0, 8, 0, stream);
        launch_gather_bf(zbuf, csr, rowoff, rdeg, aggb, 32, 4, 0, 8, 0, stream);
        launch_gemm<64, 32, 2, true, false, 8, 1, false, true>(
            bufH, aggb, Ws[2], nullptr, Bi[2], bufB, 32, 16, 0, 8, 0, 32, 24, stream,
            b3bf, 16, 8);

        // conv4: 32 -> 32, pre-agg, relu      bufB(+24 h3) -> bufB cols 64..95; dual bf16 c4
        // h3-agg (from b3bf slots 4..7) into aggb slots 8..15 (reused by conv5)
        launch_gather_bf(b3bf, csr, rowoff, rdeg, aggb, 32, 8, 4, 16, 8, stream);
        launch_gemm<32, 32, 1, true, false, 8, 1, false, true>(
            bufB, aggb, Ws[3], Wn[3], Bi[3], bufB, 64, 32, 24, 16, 8, 32, 16, stream,
            b3bf, 16, 0);

        // conv5: 64 -> 64, pre-agg, relu      bufB(+16 h4) -> bufB cols 0..63
        // gather only c4 (b3bf slots 0..3) into aggb slots 0..7; 8..15 = h3-agg
        launch_gather_bf(b3bf, csr, rowoff, rdeg, aggb, 32, 8, 0, 16, 0, stream);
        launch_gemm<64, 64, 1, true, false, 8, 2>(bufB, aggb, Ws[4], Wn[4], Bi[4],
                                                  bufB, 64, 32, 16, 16, 0, 32, 0, stream);

        // conv6: 128 -> 64, post-agg, no relu  bufB(128w) -> bufH / d_out(transposed)
        launch_gemm<128, 64, 0, false, false, 8, 2, true>(
            bufB, nullptr, Wn[5], nullptr, nullptr, zbuf, 64, 32, 0, 0, 0, 16, 0, stream);
        launch_gather_bf(zbuf, csr, rowoff, rdeg, aggb, 64, 8, 0, 16, 0, stream);
        if (last) {
            launch_gemm<128, 64, 2, false, true, 8, 2>(bufB, aggb, Ws[5], nullptr, Bi[5],
                                                       (float*)d_out, 64, 32, 0, 16, 0, 16, 0, stream);
        } else {
            // dual-write: fp32 h -> bufH (next conv1 gemm x), bf16 h -> hbf (next conv1 gather)
            launch_gemm<128, 64, 2, false, false, 8, 2, false, true>(
                bufB, aggb, Ws[5], nullptr, Bi[5], bufH, 64, 32, 0, 16, 0, 16, 0, stream,
                hbf, 16, 0);
        }
    }
}

// Round 10
// 914.375 us; speedup vs baseline: 12.1095x; 1.0686x over previous
//
#include <hip/hip_runtime.h>

#define NN 50000
#define NE 400000
#define BB 2
#define ROWS (NN * BB)   // 100000 feature rows, row r = node*2 + batch

#define SCAN_CHUNK 1024
#define SCAN_NB ((NN + SCAN_CHUNK - 1) / SCAN_CHUNK)   // 49 (<= 64)

typedef float f32x4 __attribute__((ext_vector_type(4)));
typedef short s16x8 __attribute__((ext_vector_type(8)));

__device__ inline void fma4(float4& a, float s, const float4& w) {
    a.x = fmaf(s, w.x, a.x); a.y = fmaf(s, w.y, a.y);
    a.z = fmaf(s, w.z, a.z); a.w = fmaf(s, w.w, a.w);
}
__device__ inline void add4(float4& a, const float4& v) {
    a.x += v.x; a.y += v.y; a.z += v.z; a.w += v.w;
}
__device__ inline unsigned bf1(float v) {            // fp32 -> bf16 bits (RNE)
    unsigned u = __float_as_uint(v);
    return (u + 0x7FFFu + ((u >> 16) & 1u)) >> 16;
}
__device__ inline unsigned bf2(float a, float b) {   // pack 2 floats -> 2 bf16
    return bf1(a) | (bf1(b) << 16);
}
__device__ inline void bfadd(float4& lo, float4& hi, uint4 v) {  // 8 bf16 += fp32
    lo.x += __uint_as_float(v.x << 16); lo.y += __uint_as_float(v.x & 0xFFFF0000u);
    lo.z += __uint_as_float(v.y << 16); lo.w += __uint_as_float(v.y & 0xFFFF0000u);
    hi.x += __uint_as_float(v.z << 16); hi.y += __uint_as_float(v.z & 0xFFFF0000u);
    hi.z += __uint_as_float(v.w << 16); hi.w += __uint_as_float(v.w & 0xFFFF0000u);
}

// ---------------- CSR build ----------------

__global__ void k_hist(const int* __restrict__ dst, int* __restrict__ deg) {
    int e = blockIdx.x * 256 + threadIdx.x;
    if (e < NE) atomicAdd(&deg[dst[e]], 1);
}

__global__ __launch_bounds__(256) void k_scan1(const int* __restrict__ deg,
                                               int* __restrict__ bsum) {
    int b = blockIdx.x, t = threadIdx.x;
    int base = b * SCAN_CHUNK + t * 4;
    int s = 0;
#pragma unroll
    for (int i = 0; i < 4; i++) {
        int idx = base + i;
        if (idx < NN) s += deg[idx];
    }
    for (int d = 32; d; d >>= 1) s += __shfl_down(s, d);
    __shared__ int ws[4];
    if ((t & 63) == 0) ws[t >> 6] = s;
    __syncthreads();
    if (t == 0) bsum[b] = ws[0] + ws[1] + ws[2] + ws[3];
}

__global__ void k_scan2(const int* __restrict__ bsum, int* __restrict__ boff,
                        int* __restrict__ rowoff_last) {
    int lane = threadIdx.x;   // 64 threads
    int v = (lane < SCAN_NB) ? bsum[lane] : 0;
    int incl = v;
    for (int d = 1; d < 64; d <<= 1) {
        int o = __shfl_up(incl, d);
        if (lane >= d) incl += o;
    }
    if (lane < SCAN_NB) boff[lane] = incl - v;
    if (lane == 63) rowoff_last[0] = incl;
}

__global__ __launch_bounds__(256) void k_scan3(const int* __restrict__ deg,
                                               const int* __restrict__ boff,
                                               int* __restrict__ rowoff,
                                               int* __restrict__ cursor,
                                               float* __restrict__ rdeg) {
    int b = blockIdx.x, t = threadIdx.x;
    int lane = t & 63, wv = t >> 6;
    int base = b * SCAN_CHUNK + t * 4;
    int dv[4];
    int ts = 0;
#pragma unroll
    for (int i = 0; i < 4; i++) {
        int idx = base + i;
        dv[i] = (idx < NN) ? deg[idx] : 0;
        ts += dv[i];
    }
    int incl = ts;
    for (int d = 1; d < 64; d <<= 1) {
        int o = __shfl_up(incl, d);
        if (lane >= d) incl += o;
    }
    __shared__ int wsum[4];
    if (lane == 63) wsum[wv] = incl;
    __syncthreads();
    int wexc = 0;
    for (int w = 0; w < wv; w++) wexc += wsum[w];
    int run = boff[b] + wexc + (incl - ts);
#pragma unroll
    for (int i = 0; i < 4; i++) {
        int idx = base + i;
        if (idx < NN) {
            rowoff[idx] = run;
            cursor[idx] = run;
            rdeg[idx] = 1.0f / fmaxf((float)dv[i], 1.0f);
            run += dv[i];
        }
    }
}

__global__ void k_fill(const int* __restrict__ src, const int* __restrict__ dst,
                       int* __restrict__ cursor, int* __restrict__ csr) {
    int e = blockIdx.x * 256 + threadIdx.x;
    if (e >= NE) return;
    int pos = atomicAdd(&cursor[dst[e]], 1);
    csr[pos] = src[e];
}

// ---------------- bf16 shadow pack: in_feat [B,N,64] -> hbf [ROWS][8 uint4] ----------------

__global__ void k_pack(const float4* __restrict__ in, uint4* __restrict__ out) {
    int t = blockIdx.x * 256 + threadIdx.x;
    if (t >= ROWS * 8) return;
    int r = t >> 3, k = t & 7;
    int n = r >> 1, b = r & 1;
    float4 a = in[(b * NN + n) * 16 + k * 2];
    float4 c = in[(b * NN + n) * 16 + k * 2 + 1];
    uint4 o;
    o.x = bf2(a.x, a.y); o.y = bf2(a.z, a.w);
    o.z = bf2(c.x, c.y); o.w = bf2(c.z, c.w);
    out[t] = o;
}

// ---------------- bf16 mean-aggregate ----------------
__global__ void k_gather_bf(const uint4* __restrict__ x, const int* __restrict__ csr,
                            const int* __restrict__ rowoff, const float* __restrict__ rdeg,
                            float4* __restrict__ out, int w8s, int xp8, int xo8,
                            int op4, int oo4) {
    int t = blockIdx.x * 256 + threadIdx.x;
    int n = t >> w8s, tid = t & ((1 << w8s) - 1);
    if (n >= NN) return;
    int beg = rowoff[n], end = rowoff[n + 1];
    int a0 = xo8 + tid;
    int xp2 = 2 * xp8;
    float4 a0l = {0.f,0.f,0.f,0.f}, a0h = {0.f,0.f,0.f,0.f};
    float4 a1l = {0.f,0.f,0.f,0.f}, a1h = {0.f,0.f,0.f,0.f};
    int j = beg;
    for (; j + 2 <= end; j += 2) {
        int s0 = csr[j], s1 = csr[j+1];
        int b0 = s0 * xp2 + a0, b1 = s1 * xp2 + a0;
        uint4 p0 = x[b0], q0 = x[b0 + xp8];
        uint4 p1 = x[b1], q1 = x[b1 + xp8];
        bfadd(a0l, a0h, p0); bfadd(a1l, a1h, q0);
        bfadd(a0l, a0h, p1); bfadd(a1l, a1h, q1);
    }
    if (j < end) {
        int s = csr[j];
        int b = s * xp2 + a0;
        bfadd(a0l, a0h, x[b]); bfadd(a1l, a1h, x[b + xp8]);
    }
    float rd = rdeg[n];
    float4 o0l = {a0l.x*rd, a0l.y*rd, a0l.z*rd, a0l.w*rd};
    float4 o0h = {a0h.x*rd, a0h.y*rd, a0h.z*rd, a0h.w*rd};
    float4 o1l = {a1l.x*rd, a1l.y*rd, a1l.z*rd, a1l.w*rd};
    float4 o1h = {a1h.x*rd, a1h.y*rd, a1h.z*rd, a1h.w*rd};
    int r0 = (2*n) * op4 + oo4 + 2*tid;
    int r1 = (2*n + 1) * op4 + oo4 + 2*tid;
    out[r0] = o0l; out[r0 + 1] = o0h;
    out[r1] = o1l; out[r1 + 1] = o1h;
}

// ---------------- MFMA z-gemm: z[ROWS][64] bf16 = A[ROWS][128] bf16 @ W[128][64] fp32 ----
// A rows: K 0-63 from a0 (uint4 pitch p0), K 64-127 from a1 (pitch p1).
__global__ __launch_bounds__(256) void k_zmfma(
    const uint4* __restrict__ a0, int p0, const uint4* __restrict__ a1, int p1,
    const float* __restrict__ w, unsigned short* __restrict__ z)
{
    __shared__ float wl[128 * 64];
    int t = threadIdx.x;
    for (int i = t; i < 2048; i += 256)
        ((float4*)wl)[i] = ((const float4*)w)[i];
    __syncthreads();

    int lane = t & 63, wv = t >> 6;
    int row16 = lane & 15, kq = lane >> 4;

    // B-frags: bf[kt][nt], elem j = W[kt*32 + kq*8 + j][nt*16 + row16] as bf16
    s16x8 bf[4][4];
#pragma unroll
    for (int kt = 0; kt < 4; kt++)
#pragma unroll
        for (int nt = 0; nt < 4; nt++) {
            s16x8 b;
#pragma unroll
            for (int j = 0; j < 8; j++)
                b[j] = (short)bf1(wl[(kt*32 + kq*8 + j)*64 + nt*16 + row16]);
            bf[kt][nt] = b;
        }

    for (int mt = blockIdx.x * 4 + wv; mt < ROWS / 16; mt += gridDim.x * 4) {
        int r = mt * 16 + row16;
        s16x8 av[4];
        av[0] = __builtin_bit_cast(s16x8, a0[r * p0 + kq]);
        av[1] = __builtin_bit_cast(s16x8, a0[r * p0 + 4 + kq]);
        av[2] = __builtin_bit_cast(s16x8, a1[r * p1 + kq]);
        av[3] = __builtin_bit_cast(s16x8, a1[r * p1 + 4 + kq]);
        f32x4 acc[4] = {{0.f,0.f,0.f,0.f},{0.f,0.f,0.f,0.f},
                        {0.f,0.f,0.f,0.f},{0.f,0.f,0.f,0.f}};
#pragma unroll
        for (int kt = 0; kt < 4; kt++)
#pragma unroll
            for (int nt = 0; nt < 4; nt++)
                acc[nt] = __builtin_amdgcn_mfma_f32_16x16x32_bf16(
                    av[kt], bf[kt][nt], acc[nt], 0, 0, 0);
#pragma unroll
        for (int nt = 0; nt < 4; nt++)
#pragma unroll
            for (int i = 0; i < 4; i++) {
                int ro = mt * 16 + kq * 4 + i;
                z[ro * 64 + nt * 16 + row16] = (unsigned short)bf1(acc[nt][i]);
            }
    }
}

// ---------------- tiled GEMM / SAGE transform ----------------
// MODE 0: out = x @ w0                        (OBF: write bf16, ostride4/ooff4 in uint2)
// MODE 1: out = act(x @ w0 + agg @ w1 + b)
// MODE 2: out = act(x @ w0 + agg + b)        (ABF: agg is bf16, apitch4/aoff4 in uint2)
// DUAL: additionally write bf16 copy to bfo (uint2 pitch bfp2, off bfo2).
template<int FIN, int FOUT, int MODE, bool RELU, bool TRANS,
         int RPT, int NCQ, bool OBF, bool DUAL, bool ABF>
__global__ __launch_bounds__(256) void k_gemm(
    const float* __restrict__ x, const float* __restrict__ agg,
    const float* __restrict__ w0, const float* __restrict__ w1,
    const float* __restrict__ bias, float* __restrict__ out,
    int xns4, int xbs4, int xo4, int apitch4, int aoff4, int ostride4, int ooff4,
    uint2* __restrict__ bfo, int bfp2, int bfo2)
{
    constexpr int NQ = FOUT / 4;        // col quads
    constexpr int TX = NQ / NCQ;        // threads across cols
    constexpr int TY = 256 / TX;
    constexpr int TM = TY * RPT;        // rows per block
    constexpr int W4 = FIN * NQ;        // staged float4s per matrix
    constexpr int NW = (MODE == 1) ? 2 : 1;

    __shared__ float4 wlds[NW * W4];

    int t = threadIdx.x;
    const float4* w0v = (const float4*)w0;
    for (int i = t; i < W4; i += 256) wlds[i] = w0v[i];
    if (MODE == 1) {
        const float4* w1v = (const float4*)w1;
        for (int i = t; i < W4; i += 256) wlds[W4 + i] = w1v[i];
    }
    __syncthreads();

    int tx = t % TX, ty = t / TX;
    int rbase = blockIdx.x * TM + ty * RPT;

    int xb[RPT], ab[RPT];
#pragma unroll
    for (int i = 0; i < RPT; i++) {
        int r = rbase + i;
        r = r < ROWS ? r : ROWS - 1;
        xb[i] = (r >> 1) * xns4 + (r & 1) * xbs4 + xo4;
        ab[i] = r * apitch4 + aoff4;
    }

    float4 acc[RPT][NCQ];
#pragma unroll
    for (int i = 0; i < RPT; i++)
#pragma unroll
        for (int j = 0; j < NCQ; j++) acc[i][j] = make_float4(0.f, 0.f, 0.f, 0.f);

    const float4* xv4 = (const float4*)x;
    const float4* av4 = (const float4*)agg;

    for (int k4 = 0; k4 < FIN / 4; k4++) {
        float4 wq[4][NCQ], nq[4][NCQ];
#pragma unroll
        for (int u = 0; u < 4; u++)
#pragma unroll
            for (int j = 0; j < NCQ; j++) {
                wq[u][j] = wlds[(k4 * 4 + u) * NQ + tx + j * TX];
                if (MODE == 1) nq[u][j] = wlds[W4 + (k4 * 4 + u) * NQ + tx + j * TX];
            }
#pragma unroll
        for (int i = 0; i < RPT; i++) {
            float4 xv = xv4[xb[i] + k4];
#pragma unroll
            for (int j = 0; j < NCQ; j++) {
                fma4(acc[i][j], xv.x, wq[0][j]); fma4(acc[i][j], xv.y, wq[1][j]);
                fma4(acc[i][j], xv.z, wq[2][j]); fma4(acc[i][j], xv.w, wq[3][j]);
            }
            if (MODE == 1) {
                float4 av = av4[ab[i] + k4];
#pragma unroll
                for (int j = 0; j < NCQ; j++) {
                    fma4(acc[i][j], av.x, nq[0][j]); fma4(acc[i][j], av.y, nq[1][j]);
                    fma4(acc[i][j], av.z, nq[2][j]); fma4(acc[i][j], av.w, nq[3][j]);
                }
            }
        }
    }

    float4 b4[NCQ];
#pragma unroll
    for (int j = 0; j < NCQ; j++) {
        b4[j] = make_float4(0.f, 0.f, 0.f, 0.f);
        if (MODE != 0) b4[j] = *(const float4*)&bias[(tx + j * TX) * 4];
    }

#pragma unroll
    for (int i = 0; i < RPT; i++) {
        int r = rbase + i;
        if (r >= ROWS) continue;
#pragma unroll
        for (int j = 0; j < NCQ; j++) {
            int q = tx + j * TX;
            float4 v = acc[i][j];
            if (MODE == 2) {
                if (ABF) {
                    uint2 u = ((const uint2*)agg)[ab[i] + q];
                    v.x += __uint_as_float(u.x << 16);
                    v.y += __uint_as_float(u.x & 0xFFFF0000u);
                    v.z += __uint_as_float(u.y << 16);
                    v.w += __uint_as_float(u.y & 0xFFFF0000u);
                } else {
                    float4 ag = av4[ab[i] + q];
                    add4(v, ag);
                }
            }
            if (MODE != 0) add4(v, b4[j]);
            if (RELU) {
                v.x = fmaxf(v.x, 0.f); v.y = fmaxf(v.y, 0.f);
                v.z = fmaxf(v.z, 0.f); v.w = fmaxf(v.w, 0.f);
            }
            if (OBF) {
                uint2 w; w.x = bf2(v.x, v.y); w.y = bf2(v.z, v.w);
                ((uint2*)out)[r * ostride4 + ooff4 + q] = w;
            } else {
                int oidx;
                if (TRANS) {                   // FOUT==64 here
                    int n = r >> 1, b = r & 1;
                    oidx = b * (NN * 16) + n * 16 + q;
                } else {
                    oidx = r * ostride4 + ooff4 + q;
                }
                ((float4*)out)[oidx] = v;
            }
            if (DUAL) {
                uint2 w; w.x = bf2(v.x, v.y); w.y = bf2(v.z, v.w);
                bfo[r * bfp2 + bfo2 + q] = w;
            }
        }
    }
}

// ---------------- host ----------------

template<int FIN, int FOUT, int MODE, bool RELU, bool TRANS,
         int RPT = 8, int NCQ = 1, bool OBF = false, bool DUAL = false, bool ABF = false>
static void launch_gemm(const float* x, const float* agg, const float* w0, const float* w1,
                        const float* bias, float* out, int xns4, int xbs4, int xo4,
                        int apitch4, int aoff4, int ostride4, int ooff4,
                        hipStream_t stream,
                        uint2* bfo = nullptr, int bfp2 = 0, int bfo2 = 0) {
    constexpr int TM = (256 / (FOUT / 4 / NCQ)) * RPT;
    int nb = (ROWS + TM - 1) / TM;
    k_gemm<FIN, FOUT, MODE, RELU, TRANS, RPT, NCQ, OBF, DUAL, ABF><<<nb, 256, 0, stream>>>(
        x, agg, w0, w1, bias, out, xns4, xbs4, xo4, apitch4, aoff4, ostride4, ooff4,
        bfo, bfp2, bfo2);
}

static void launch_gather_bf(const void* xbf, const int* csr, const int* rowoff,
                             const float* rdeg, float* aggb, int width,
                             int xp8, int xo8, int op4, int oo4, hipStream_t stream) {
    int w8s = 0;
    while ((1 << w8s) < width / 8) w8s++;
    int gt = NN << w8s;
    k_gather_bf<<<(gt + 255) / 256, 256, 0, stream>>>(
        (const uint4*)xbf, csr, rowoff, rdeg, (float4*)aggb, w8s, xp8, xo8, op4, oo4);
}

extern "C" void kernel_launch(void* const* d_in, const int* in_sizes, int n_in,
                              void* d_out, int out_size, void* d_ws, size_t ws_size,
                              hipStream_t stream) {
    const float* in_feat = (const float*)d_in[0];
    const int* src = (const int*)d_in[1];
    const int* dst = (const int*)d_in[2];
    const float* Ws[6], *Wn[6], *Bi[6];
    for (int i = 0; i < 6; i++) {
        Ws[i] = (const float*)d_in[3 + 3 * i];
        Wn[i] = (const float*)d_in[4 + 3 * i];
        Bi[i] = (const float*)d_in[5 + 3 * i];
    }

    char* ws = (char*)d_ws;
    size_t off = 0;
    auto alloc = [&](size_t bytes) {
        void* p = ws + off;
        off = (off + bytes + 255) & ~(size_t)255;
        return p;
    };
    float* rdeg   = (float*)alloc((size_t)NN * 4);
    int*   deg    = (int*)  alloc((size_t)NN * 4);
    int*   rowoff = (int*)  alloc((size_t)(NN + 1) * 4);
    int*   cursor = (int*)  alloc((size_t)NN * 4);
    int*   csr    = (int*)  alloc((size_t)NE * 4);
    int*   bsum   = (int*)  alloc((size_t)SCAN_NB * 4);
    int*   boff   = (int*)  alloc((size_t)SCAN_NB * 4);
    float* bufH   = (float*)alloc((size_t)ROWS * 64 * 4);    // h2 mid-step; h between steps
    float* bufA   = (float*)alloc((size_t)ROWS * 128 * 4);   // h1 fp32 (conv1B..conv2-final)
    float* bufB   = (float*)alloc((size_t)ROWS * 128 * 4);   // h5 concat home [c5|c4|h3]
    float* aggb   = (float*)alloc((size_t)ROWS * 64 * 4);    // packed fp32 agg, 64w
    float* zbuf   = (float*)d_out;   // bf16 z scratch; dead before final d_out write

    // bf16 shadows / tmps aliasing dead windows:
    //  bufA-lo  [0,        ROWS*32):  hbf  (h bf16, conv6-dual .. next conv1-gather)
    //  bufA     [ROWS*32,  ROWS*64):  b3bf ([c4|h3] bf16, conv3/4-dual .. conv5-gather/conv6-z)
    //  bufA     [ROWS*64,  ROWS*96):  c5bf (c5 bf16, conv5-dual .. conv6-z)
    //  bufB     [0,        ROWS*64):  tmp1 (conv1 neigh-term bf16 128w, conv1A .. conv1B)
    //  bufB     [ROWS*64,  ROWS*128): h1bf (h1 bf16 128w, conv1B .. conv2-z)
    uint2* hbf  = (uint2*)bufA;
    uint2* b3bf = (uint2*)(bufA + (size_t)ROWS * 32);
    uint2* c5bf = (uint2*)(bufA + (size_t)ROWS * 64);
    uint2* tmp1 = (uint2*)bufB;
    uint2* h1bf = (uint2*)(bufB + (size_t)ROWS * 64);

    // CSR build (ws re-poisoned every call)
    hipMemsetAsync(deg, 0, (size_t)NN * 4, stream);
    k_hist<<<(NE + 255) / 256, 256, 0, stream>>>(dst, deg);
    k_scan1<<<SCAN_NB, 256, 0, stream>>>(deg, bsum);
    k_scan2<<<1, 64, 0, stream>>>(bsum, boff, rowoff + NN);
    k_scan3<<<SCAN_NB, 256, 0, stream>>>(deg, boff, rowoff, cursor, rdeg);
    k_fill<<<(NE + 255) / 256, 256, 0, stream>>>(src, dst, cursor, csr);

    // bf16 pack of in_feat for step-1 conv1 gather
    k_pack<<<(ROWS * 8 + 255) / 256, 256, 0, stream>>>((const float4*)in_feat, (uint4*)hbf);

    const int BSTR = NN * 16;   // in_feat batch stride (float4)

    for (int s = 0; s < 2; s++) {
        int last = (s == 1);
        const float* hx = s ? bufH : in_feat;
        int hns = s ? 32 : 16, hbs = s ? 16 : BSTR;

        // conv1: 64 -> 128, pre-agg, relu.  Split into two 32KB-LDS passes.
        launch_gather_bf(hbf, csr, rowoff, rdeg, aggb, 64, 8, 0, 16, 0, stream);
        // passA: tmp1 = agg @ Wn (bf16 out, 128w)
        launch_gemm<64, 128, 0, false, false, 8, 2, true>(
            aggb, nullptr, Wn[0], nullptr, nullptr, (float*)tmp1,
            32, 16, 0, 0, 0, 32, 0, stream);
        // passB: h1 = relu(x @ Ws + tmp1 + b) -> bufA fp32 + h1bf dual
        launch_gemm<64, 128, 2, true, false, 8, 2, false, true, true>(
            hx, (const float*)tmp1, Ws[0], nullptr, Bi[0], bufA,
            hns, hbs, 0, 32, 0, 32, 0, stream, h1bf, 32, 0);

        // conv2: 128 -> 64, post-agg, relu    (z via MFMA from h1bf)
        k_zmfma<<<256, 256, 0, stream>>>(
            (const uint4*)h1bf, 16, (const uint4*)h1bf + 8, 16, Wn[1],
            (unsigned short*)zbuf);
        launch_gather_bf(zbuf, csr, rowoff, rdeg, aggb, 64, 8, 0, 16, 0, stream);
        launch_gemm<128, 64, 2, true, false, 8, 2>(bufA, aggb, Ws[1], nullptr, Bi[1],
                                                   bufH, 64, 32, 0, 16, 0, 16, 0, stream);

        // conv3: 64 -> 32, post-agg, relu     bufH -> bufB cols 96..127; dual bf16 h3
        launch_gemm<64, 32, 0, false, false, 8, 1, true>(
            bufH, nullptr, Wn[2], nullptr, nullptr, zbuf, 32, 16, 0, 0, 0, 8, 0, stream);
        launch_gather_bf(zbuf, csr, rowoff, rdeg, aggb, 32, 4, 0, 8, 0, stream);
        launch_gemm<64, 32, 2, true, false, 8, 1, false, true>(
            bufH, aggb, Ws[2], nullptr, Bi[2], bufB, 32, 16, 0, 8, 0, 32, 24, stream,
            b3bf, 16, 8);

        // conv4: 32 -> 32, pre-agg, relu      bufB(+24 h3) -> bufB cols 64..95; dual bf16 c4
        launch_gather_bf(b3bf, csr, rowoff, rdeg, aggb, 32, 8, 4, 16, 8, stream);
        launch_gemm<32, 32, 1, true, false, 8, 1, false, true>(
            bufB, aggb, Ws[3], Wn[3], Bi[3], bufB, 64, 32, 24, 16, 8, 32, 16, stream,
            b3bf, 16, 0);

        // conv5: 64 -> 64, pre-agg, relu      bufB(+16 h4) -> bufB cols 0..63; dual bf16 c5
        launch_gather_bf(b3bf, csr, rowoff, rdeg, aggb, 32, 8, 0, 16, 0, stream);
        launch_gemm<64, 64, 1, true, false, 8, 2, false, true>(
            bufB, aggb, Ws[4], Wn[4], Bi[4], bufB, 64, 32, 16, 16, 0, 32, 0, stream,
            c5bf, 16, 0);

        // conv6: 128 -> 64, post-agg, no relu  (z via MFMA from [c5bf | b3bf])
        k_zmfma<<<256, 256, 0, stream>>>(
            (const uint4*)c5bf, 8, (const uint4*)b3bf, 8, Wn[5],
            (unsigned short*)zbuf);
        launch_gather_bf(zbuf, csr, rowoff, rdeg, aggb, 64, 8, 0, 16, 0, stream);
        if (last) {
            launch_gemm<128, 64, 2, false, true, 8, 2>(bufB, aggb, Ws[5], nullptr, Bi[5],
                                                       (float*)d_out, 64, 32, 0, 16, 0, 16, 0, stream);
        } else {
            launch_gemm<128, 64, 2, false, false, 8, 2, false, true>(
                bufB, aggb, Ws[5], nullptr, Bi[5], bufH, 64, 32, 0, 16, 0, 16, 0, stream,
                hbf, 16, 0);
        }
    }
}